// Round 1
// baseline (996.164 us; speedup 1.0000x reference)
//
#include <hip/hip_runtime.h>
#include <hip/hip_bf16.h>
#include <math.h>

// ---------------------------------------------------------------------------
// GAT 3-layer forward. N=20000 nodes, E=320000 edges (+N self loops).
// L0: in=128 -> H=8,C=32 (concat 256) -> BN -> ReLU
// L1: 256 -> H=8,C=32 (concat 256) -> BN -> ReLU
// L2: 256 -> H=1,C=16 -> +b2 -> log_softmax
// All fp32. Edge softmax via atomicMax(encoded)/atomicAdd; aggregate via
// per-edge block with 256 atomicAdds. Correctness-first baseline.
// ---------------------------------------------------------------------------

#define LRELU(v) ((v) > 0.f ? (v) : 0.2f * (v))

__device__ __forceinline__ unsigned enc_f32(float f) {
    unsigned u = __float_as_uint(f);
    return (u & 0x80000000u) ? ~u : (u | 0x80000000u);
}
__device__ __forceinline__ float dec_f32(unsigned u) {
    return (u & 0x80000000u) ? __uint_as_float(u & 0x7fffffffu)
                             : __uint_as_float(~u);
}
// enc(-inf) = ~0xFF800000
#define ENC_NEG_INF 0x007FFFFFu

// -------------------------- fills ------------------------------------------
__global__ void fill_f32_k(float* p, float v, int n) {
    int i = blockIdx.x * 256 + threadIdx.x;
    if (i < n) p[i] = v;
}
__global__ void fill_u32_k(unsigned* p, unsigned v, int n) {
    int i = blockIdx.x * 256 + threadIdx.x;
    if (i < n) p[i] = v;
}

// -------------------------- GEMM: Y[M,OUT] = X[M,IN] @ W[IN,OUT] ------------
template <int IN, int OUT>
__global__ void gemm_k(const float* __restrict__ X, const float* __restrict__ W,
                       float* __restrict__ Y, int M) {
    constexpr int ROWS = 32;
    constexpr int GROUPS = 256 / OUT;          // 1 for OUT=256, 16 for OUT=16
    constexpr int RPT = ROWS / (GROUPS ? GROUPS : 1);
    __shared__ float xs[ROWS][IN];
    const int row0 = blockIdx.x * ROWS;
    const int tid = threadIdx.x;
    for (int idx = tid; idx < ROWS * IN; idx += 256) {
        int r = idx / IN, k = idx % IN;
        int gr = row0 + r;
        xs[r][k] = (gr < M) ? X[gr * IN + k] : 0.f;
    }
    __syncthreads();
    const int j = tid % OUT;
    const int rbase = (tid / OUT) * RPT;
    float acc[RPT];
#pragma unroll
    for (int r = 0; r < RPT; r++) acc[r] = 0.f;
    for (int k = 0; k < IN; k++) {
        float w = W[k * OUT + j];
#pragma unroll
        for (int r = 0; r < RPT; r++) acc[r] += xs[rbase + r][k] * w;
    }
#pragma unroll
    for (int r = 0; r < RPT; r++) {
        int gr = row0 + rbase + r;
        if (gr < M) Y[gr * OUT + j] = acc[r];
    }
}

// -------------------------- per-node logits, H=8 C=32 -----------------------
__global__ void logits8_k(const float* __restrict__ feat,
                          const float* __restrict__ as,
                          const float* __restrict__ ad,
                          float* __restrict__ als, float* __restrict__ ald,
                          int N) {
    int n = blockIdx.x;
    int tid = threadIdx.x;            // 256
    int h = tid >> 5, c = tid & 31;
    float v = feat[n * 256 + tid];
    float ps = v * as[h * 32 + c];
    float pd = v * ad[h * 32 + c];
    for (int off = 16; off; off >>= 1) {
        ps += __shfl_xor(ps, off, 32);
        pd += __shfl_xor(pd, off, 32);
    }
    if (c == 0) {
        als[n * 8 + h] = ps;
        ald[n * 8 + h] = pd;
    }
}

// H=1 C=16: one block handles 16 nodes
__global__ void logits1_k(const float* __restrict__ feat,
                          const float* __restrict__ as,
                          const float* __restrict__ ad,
                          float* __restrict__ als, float* __restrict__ ald,
                          int N) {
    int tid = threadIdx.x;
    int n = blockIdx.x * 16 + (tid >> 4);
    int c = tid & 15;
    if (n >= N) return;
    float v = feat[n * 16 + c];
    float ps = v * as[c], pd = v * ad[c];
    for (int off = 8; off; off >>= 1) {
        ps += __shfl_xor(ps, off, 16);
        pd += __shfl_xor(pd, off, 16);
    }
    if (c == 0) { als[n] = ps; ald[n] = pd; }
}

// -------------------------- edge passes, H=8 --------------------------------
__device__ __forceinline__ void edge_sd(const int* __restrict__ ei, int E,
                                        int e, int& s, int& d) {
    if (e < E) { s = ei[e]; d = ei[E + e]; }
    else       { s = d = e - E; }
}

__global__ void edge_max8_k(const int* __restrict__ ei, int E, int N,
                            const float* __restrict__ als,
                            const float* __restrict__ ald,
                            unsigned* __restrict__ emax) {
    int gid = blockIdx.x * 256 + threadIdx.x;
    int tot = (E + N) * 8;
    if (gid >= tot) return;
    int e = gid >> 3, h = gid & 7;
    int s, d; edge_sd(ei, E, e, s, d);
    float v = als[s * 8 + h] + ald[d * 8 + h];
    v = LRELU(v);
    atomicMax(&emax[d * 8 + h], enc_f32(v));
}

__global__ void edge_sum8_k(const int* __restrict__ ei, int E, int N,
                            const float* __restrict__ als,
                            const float* __restrict__ ald,
                            const unsigned* __restrict__ emax,
                            float* __restrict__ denom) {
    int gid = blockIdx.x * 256 + threadIdx.x;
    int tot = (E + N) * 8;
    if (gid >= tot) return;
    int e = gid >> 3, h = gid & 7;
    int s, d; edge_sd(ei, E, e, s, d);
    float v = als[s * 8 + h] + ald[d * 8 + h];
    v = LRELU(v);
    float p = expf(v - dec_f32(emax[d * 8 + h]));
    atomicAdd(&denom[d * 8 + h], p);
}

// one block (256 threads) per edge: tid = h*32 + c over the 256 channels
__global__ void edge_agg8_k(const int* __restrict__ ei, int E, int N,
                            const float* __restrict__ als,
                            const float* __restrict__ ald,
                            const unsigned* __restrict__ emax,
                            const float* __restrict__ denom,
                            const float* __restrict__ feat,
                            float* __restrict__ agg) {
    int e = blockIdx.x;
    int tid = threadIdx.x;
    int s, d; edge_sd(ei, E, e, s, d);
    int h = tid >> 5;
    float v = als[s * 8 + h] + ald[d * 8 + h];
    v = LRELU(v);
    float alpha = expf(v - dec_f32(emax[d * 8 + h])) / denom[d * 8 + h];
    atomicAdd(&agg[d * 256 + tid], feat[s * 256 + tid] * alpha);
}

// -------------------------- edge passes, H=1 --------------------------------
__global__ void edge_max1_k(const int* __restrict__ ei, int E, int N,
                            const float* __restrict__ als,
                            const float* __restrict__ ald,
                            unsigned* __restrict__ emax) {
    int e = blockIdx.x * 256 + threadIdx.x;
    if (e >= E + N) return;
    int s, d; edge_sd(ei, E, e, s, d);
    float v = als[s] + ald[d];
    v = LRELU(v);
    atomicMax(&emax[d], enc_f32(v));
}

__global__ void edge_sum1_k(const int* __restrict__ ei, int E, int N,
                            const float* __restrict__ als,
                            const float* __restrict__ ald,
                            const unsigned* __restrict__ emax,
                            float* __restrict__ denom) {
    int e = blockIdx.x * 256 + threadIdx.x;
    if (e >= E + N) return;
    int s, d; edge_sd(ei, E, e, s, d);
    float v = als[s] + ald[d];
    v = LRELU(v);
    atomicAdd(&denom[d], expf(v - dec_f32(emax[d])));
}

// 16 edges per block, 16 channels per edge
__global__ void edge_agg1_k(const int* __restrict__ ei, int E, int N,
                            const float* __restrict__ als,
                            const float* __restrict__ ald,
                            const unsigned* __restrict__ emax,
                            const float* __restrict__ denom,
                            const float* __restrict__ feat,
                            float* __restrict__ agg) {
    int tid = threadIdx.x;
    int e = blockIdx.x * 16 + (tid >> 4);
    int c = tid & 15;
    if (e >= E + N) return;
    int s, d; edge_sd(ei, E, e, s, d);
    float v = als[s] + ald[d];
    v = LRELU(v);
    float alpha = expf(v - dec_f32(emax[d])) / denom[d];
    atomicAdd(&agg[d * 16 + c], feat[s * 16 + c] * alpha);
}

// -------------------------- batchnorm ---------------------------------------
__global__ void bn_stats_k(const float* __restrict__ agg,
                           const float* __restrict__ b,
                           float* __restrict__ stats, int N) {
    int ch = threadIdx.x;             // 256
    int r0 = blockIdx.x * 64;
    int r1 = r0 + 64 < N ? r0 + 64 : N;
    float s = 0.f, s2 = 0.f;
    for (int r = r0; r < r1; r++) {
        float v = agg[r * 256 + ch] + b[ch];
        s += v; s2 += v * v;
    }
    atomicAdd(&stats[ch], s);
    atomicAdd(&stats[256 + ch], s2);
}

__global__ void bn_apply_k(const float* __restrict__ agg,
                           const float* __restrict__ b,
                           const float* __restrict__ stats,
                           const float* __restrict__ g,
                           const float* __restrict__ be,
                           float* __restrict__ outp, int N) {
    int gid = blockIdx.x * 256 + threadIdx.x;
    if (gid >= N * 256) return;
    int ch = gid & 255;
    float invN = 1.f / (float)N;
    float mu = stats[ch] * invN;
    float var = stats[256 + ch] * invN - mu * mu;
    float v = (agg[gid] + b[ch] - mu) * rsqrtf(var + 1e-5f) * g[ch] + be[ch];
    outp[gid] = v > 0.f ? v : 0.f;
}

// -------------------------- final log_softmax -------------------------------
__global__ void final_ls_k(const float* __restrict__ agg2,
                           const float* __restrict__ b2,
                           float* __restrict__ out, int N) {
    int tid = threadIdx.x;
    int n = blockIdx.x * 16 + (tid >> 4);
    int c = tid & 15;
    if (n >= N) return;
    float v = agg2[n * 16 + c] + b2[c];
    float m = v;
    for (int off = 8; off; off >>= 1) m = fmaxf(m, __shfl_xor(m, off, 16));
    float e = expf(v - m);
    float s = e;
    for (int off = 8; off; off >>= 1) s += __shfl_xor(s, off, 16);
    out[n * 16 + c] = v - m - logf(s);
}

// ---------------------------------------------------------------------------
extern "C" void kernel_launch(void* const* d_in, const int* in_sizes, int n_in,
                              void* d_out, int out_size, void* d_ws, size_t ws_size,
                              hipStream_t stream) {
    const float* x   = (const float*)d_in[0];
    const int*   ei  = (const int*)d_in[1];
    const float* W0  = (const float*)d_in[2];
    const float* as0 = (const float*)d_in[3];
    const float* ad0 = (const float*)d_in[4];
    const float* b0  = (const float*)d_in[5];
    const float* g0  = (const float*)d_in[6];
    const float* be0 = (const float*)d_in[7];
    const float* W1  = (const float*)d_in[8];
    const float* as1 = (const float*)d_in[9];
    const float* ad1 = (const float*)d_in[10];
    const float* b1  = (const float*)d_in[11];
    const float* g1  = (const float*)d_in[12];
    const float* be1 = (const float*)d_in[13];
    const float* W2  = (const float*)d_in[14];
    const float* as2 = (const float*)d_in[15];
    const float* ad2 = (const float*)d_in[16];
    const float* b2  = (const float*)d_in[17];
    float* out = (float*)d_out;

    const int N = in_sizes[0] / 128;       // 20000
    const int E = in_sizes[1] / 2;         // 320000
    const int ET = E + N;                  // with self loops

    float* ws = (float*)d_ws;
    size_t o = 0;
    float* hbuf = ws + o;  o += (size_t)N * 256;
    float* bufB = ws + o;  o += (size_t)N * 256;
    float* als  = ws + o;  o += (size_t)N * 8;
    float* ald  = ws + o;  o += (size_t)N * 8;
    unsigned* emax = (unsigned*)(ws + o); o += (size_t)N * 8;
    float* denom = ws + o; o += (size_t)N * 8;
    float* stats = ws + o; o += 512;
    float* h2   = ws + o;  o += (size_t)N * 16;
    float* agg2 = ws + o;  o += (size_t)N * 16;
    float* als2 = ws + o;  o += (size_t)N;
    float* ald2 = ws + o;  o += (size_t)N;
    unsigned* emax2 = (unsigned*)(ws + o); o += (size_t)N;
    float* denom2 = ws + o; o += (size_t)N;

    const int gRows = (N + 31) / 32;
    const int gNH   = (N * 8 + 255) / 256;
    const int gEH   = (ET * 8 + 255) / 256;
    const int gE    = (ET + 255) / 256;
    const int gN256 = (N * 256 + 255) / 256;
    const int gBN   = (N + 63) / 64;

    // ---------------- Layer 0 ----------------
    gemm_k<128, 256><<<gRows, 256, 0, stream>>>(x, W0, hbuf, N);
    logits8_k<<<N, 256, 0, stream>>>(hbuf, as0, ad0, als, ald, N);
    fill_u32_k<<<gNH, 256, 0, stream>>>(emax, ENC_NEG_INF, N * 8);
    fill_f32_k<<<gNH, 256, 0, stream>>>(denom, 0.f, N * 8);
    fill_f32_k<<<gN256, 256, 0, stream>>>(bufB, 0.f, N * 256);
    edge_max8_k<<<gEH, 256, 0, stream>>>(ei, E, N, als, ald, emax);
    edge_sum8_k<<<gEH, 256, 0, stream>>>(ei, E, N, als, ald, emax, denom);
    edge_agg8_k<<<ET, 256, 0, stream>>>(ei, E, N, als, ald, emax, denom, hbuf, bufB);
    fill_f32_k<<<2, 256, 0, stream>>>(stats, 0.f, 512);
    bn_stats_k<<<gBN, 256, 0, stream>>>(bufB, b0, stats, N);
    bn_apply_k<<<gN256, 256, 0, stream>>>(bufB, b0, stats, g0, be0, hbuf, N);

    // ---------------- Layer 1 ----------------
    gemm_k<256, 256><<<gRows, 256, 0, stream>>>(hbuf, W1, bufB, N);
    logits8_k<<<N, 256, 0, stream>>>(bufB, as1, ad1, als, ald, N);
    fill_u32_k<<<gNH, 256, 0, stream>>>(emax, ENC_NEG_INF, N * 8);
    fill_f32_k<<<gNH, 256, 0, stream>>>(denom, 0.f, N * 8);
    fill_f32_k<<<gN256, 256, 0, stream>>>(hbuf, 0.f, N * 256);
    edge_max8_k<<<gEH, 256, 0, stream>>>(ei, E, N, als, ald, emax);
    edge_sum8_k<<<gEH, 256, 0, stream>>>(ei, E, N, als, ald, emax, denom);
    edge_agg8_k<<<ET, 256, 0, stream>>>(ei, E, N, als, ald, emax, denom, bufB, hbuf);
    fill_f32_k<<<2, 256, 0, stream>>>(stats, 0.f, 512);
    bn_stats_k<<<gBN, 256, 0, stream>>>(hbuf, b1, stats, N);
    bn_apply_k<<<gN256, 256, 0, stream>>>(hbuf, b1, stats, g1, be1, bufB, N);

    // ---------------- Layer 2 ----------------
    gemm_k<256, 16><<<gRows, 256, 0, stream>>>(bufB, W2, h2, N);
    logits1_k<<<(N + 15) / 16, 256, 0, stream>>>(h2, as2, ad2, als2, ald2, N);
    fill_u32_k<<<(N + 255) / 256, 256, 0, stream>>>(emax2, ENC_NEG_INF, N);
    fill_f32_k<<<(N + 255) / 256, 256, 0, stream>>>(denom2, 0.f, N);
    fill_f32_k<<<(N * 16 + 255) / 256, 256, 0, stream>>>(agg2, 0.f, N * 16);
    edge_max1_k<<<gE, 256, 0, stream>>>(ei, E, N, als2, ald2, emax2);
    edge_sum1_k<<<gE, 256, 0, stream>>>(ei, E, N, als2, ald2, emax2, denom2);
    edge_agg1_k<<<(ET + 15) / 16, 256, 0, stream>>>(ei, E, N, als2, ald2, emax2,
                                                    denom2, h2, agg2);
    final_ls_k<<<(N + 15) / 16, 256, 0, stream>>>(agg2, b2, out, N);
}

// Round 2
// 522.058 us; speedup vs baseline: 1.9081x; 1.9081x over previous
//
#include <hip/hip_runtime.h>
#include <hip/hip_bf16.h>
#include <math.h>

// ---------------------------------------------------------------------------
// GAT 3-layer forward. N=20000 nodes, E=320000 edges (+N self loops).
// Round 2: replace atomic edge-scatter with per-call CSR (dst-sorted) and
// one-wave-per-node two-pass softmax-aggregate. No fp atomics in hot path.
// ---------------------------------------------------------------------------

#define LRELU(v) ((v) > 0.f ? (v) : 0.2f * (v))

// -------------------------- fills ------------------------------------------
__global__ void fill_u32_k(unsigned* p, unsigned v, int n) {
    int i = blockIdx.x * 256 + threadIdx.x;
    if (i < n) p[i] = v;
}

// -------------------------- CSR build --------------------------------------
__global__ void hist_k(const int* __restrict__ ei, int E, int N,
                       int* __restrict__ deg) {
    int e = blockIdx.x * 256 + threadIdx.x;
    if (e >= E + N) return;
    int d = (e < E) ? ei[E + e] : (e - E);
    atomicAdd(&deg[d], 1);
}

// single block, 256 threads: exclusive scan of deg -> rowptr, cnt
__global__ void scan_k(const int* __restrict__ deg, int* __restrict__ rowptr,
                       int* __restrict__ cnt, int N) {
    __shared__ int part[256];
    int tid = threadIdx.x;
    int chunk = (N + 255) >> 8;
    int b = tid * chunk;
    int e = b + chunk < N ? b + chunk : N;
    int s = 0;
    for (int i = b; i < e; i++) s += deg[i];
    part[tid] = s;
    __syncthreads();
    for (int d = 1; d < 256; d <<= 1) {
        int v = (tid >= d) ? part[tid - d] : 0;
        __syncthreads();
        part[tid] += v;
        __syncthreads();
    }
    int prefix = (tid == 0) ? 0 : part[tid - 1];
    for (int i = b; i < e; i++) {
        rowptr[i] = prefix;
        cnt[i] = prefix;
        prefix += deg[i];
    }
    if (tid == 255) rowptr[N] = prefix;
}

__global__ void scatter_k(const int* __restrict__ ei, int E, int N,
                          int* __restrict__ cnt, int* __restrict__ ssrc) {
    int e = blockIdx.x * 256 + threadIdx.x;
    if (e >= E + N) return;
    int s, d;
    if (e < E) { s = ei[e]; d = ei[E + e]; }
    else       { s = d = e - E; }
    int pos = atomicAdd(&cnt[d], 1);
    ssrc[pos] = s;
}

// -------------------------- GEMM: Y[M,OUT] = X[M,IN] @ W[IN,OUT] ------------
template <int IN, int OUT>
__global__ void gemm_k(const float* __restrict__ X, const float* __restrict__ W,
                       float* __restrict__ Y, int M) {
    constexpr int ROWS = 32;
    constexpr int GROUPS = 256 / OUT;
    constexpr int RPT = ROWS / (GROUPS ? GROUPS : 1);
    __shared__ float xs[ROWS][IN];
    const int row0 = blockIdx.x * ROWS;
    const int tid = threadIdx.x;
    for (int idx = tid; idx < ROWS * IN; idx += 256) {
        int r = idx / IN, k = idx % IN;
        int gr = row0 + r;
        xs[r][k] = (gr < M) ? X[gr * IN + k] : 0.f;
    }
    __syncthreads();
    const int j = tid % OUT;
    const int rbase = (tid / OUT) * RPT;
    float acc[RPT];
#pragma unroll
    for (int r = 0; r < RPT; r++) acc[r] = 0.f;
    for (int k = 0; k < IN; k++) {
        float w = W[k * OUT + j];
#pragma unroll
        for (int r = 0; r < RPT; r++) acc[r] += xs[rbase + r][k] * w;
    }
#pragma unroll
    for (int r = 0; r < RPT; r++) {
        int gr = row0 + rbase + r;
        if (gr < M) Y[gr * OUT + j] = acc[r];
    }
}

// -------------------------- per-node logits, H=8 C=32 -----------------------
__global__ void logits8_k(const float* __restrict__ feat,
                          const float* __restrict__ as,
                          const float* __restrict__ ad,
                          float* __restrict__ als, float* __restrict__ ald,
                          int N) {
    int n = blockIdx.x;
    int tid = threadIdx.x;            // 256
    int h = tid >> 5, c = tid & 31;
    float v = feat[n * 256 + tid];
    float ps = v * as[h * 32 + c];
    float pd = v * ad[h * 32 + c];
    for (int off = 16; off; off >>= 1) {
        ps += __shfl_xor(ps, off, 32);
        pd += __shfl_xor(pd, off, 32);
    }
    if (c == 0) {
        als[n * 8 + h] = ps;
        ald[n * 8 + h] = pd;
    }
}

// H=1 C=16: one block handles 16 nodes
__global__ void logits1_k(const float* __restrict__ feat,
                          const float* __restrict__ as,
                          const float* __restrict__ ad,
                          float* __restrict__ als, float* __restrict__ ald,
                          int N) {
    int tid = threadIdx.x;
    int n = blockIdx.x * 16 + (tid >> 4);
    int c = tid & 15;
    if (n >= N) return;
    float v = feat[n * 16 + c];
    float ps = v * as[c], pd = v * ad[c];
    for (int off = 8; off; off >>= 1) {
        ps += __shfl_xor(ps, off, 16);
        pd += __shfl_xor(pd, off, 16);
    }
    if (c == 0) { als[n] = ps; ald[n] = pd; }
}

// -------------------------- CSR aggregate, H=8 C=32 -------------------------
// one wave per node (4 waves / block). Pass 1: per-head max over incoming
// edges (each lane tracks its own head, redundant within the 8-lane group).
// Pass 2: sequential over edges, coalesced float4 gather of feat[src].
__global__ void agg8_csr_k(const int* __restrict__ rowptr,
                           const int* __restrict__ ssrc,
                           const float* __restrict__ als,
                           const float* __restrict__ ald,
                           const float* __restrict__ feat,
                           float* __restrict__ agg, int N) {
    int lane = threadIdx.x & 63;
    int n = blockIdx.x * 4 + (threadIdx.x >> 6);
    if (n >= N) return;
    const int r0 = rowptr[n], r1 = rowptr[n + 1];
    const int h0 = lane >> 3;          // head owned by this lane (pass 1/2 logit)
    const int c0 = lane << 2;          // 4 channels owned in pass 2
    const int hc = c0 >> 5;            // head of the owned channels
    float adh = ald[n * 8 + h0];
    float adc = ald[n * 8 + hc];

    float mh = -1e30f;
    for (int e = r0; e < r1; e++) {
        int s = ssrc[e];               // wave-uniform -> broadcast load
        float v = als[s * 8 + h0] + adh;
        mh = fmaxf(mh, LRELU(v));
    }
    // every lane of a head-group computed the identical max; redistribute so
    // each lane gets the max of the head its CHANNELS belong to.
    float mc = __shfl(mh, hc << 3);

    float4 acc = {0.f, 0.f, 0.f, 0.f};
    float den = 0.f;
    for (int e = r0; e < r1; e++) {
        int s = ssrc[e];
        float v = als[s * 8 + hc] + adc;
        v = LRELU(v);
        float p = __expf(v - mc);
        den += p;                      // identical across the 8-lane group
        float4 f = *reinterpret_cast<const float4*>(feat + (size_t)s * 256 + c0);
        acc.x += f.x * p; acc.y += f.y * p; acc.z += f.z * p; acc.w += f.w * p;
    }
    float inv = 1.f / den;
    acc.x *= inv; acc.y *= inv; acc.z *= inv; acc.w *= inv;
    *reinterpret_cast<float4*>(agg + (size_t)n * 256 + c0) = acc;
}

// -------------------------- CSR aggregate + log_softmax, H=1 C=16 -----------
__global__ void agg1_ls_k(const int* __restrict__ rowptr,
                          const int* __restrict__ ssrc,
                          const float* __restrict__ als,
                          const float* __restrict__ ald,
                          const float* __restrict__ feat,
                          const float* __restrict__ b2,
                          float* __restrict__ out, int N) {
    int lane = threadIdx.x & 63;
    int n = blockIdx.x * 4 + (threadIdx.x >> 6);
    if (n >= N) return;
    const int r0 = rowptr[n], r1 = rowptr[n + 1];
    float adh = ald[n];

    float mh = -1e30f;
    for (int e = r0 + lane; e < r1; e += 64) {
        int s = ssrc[e];
        float v = als[s] + adh;
        mh = fmaxf(mh, LRELU(v));
    }
#pragma unroll
    for (int off = 32; off; off >>= 1) mh = fmaxf(mh, __shfl_xor(mh, off));

    // 4 edge slots x 16 channels
    int slot = lane >> 4, c = lane & 15;
    float acc = 0.f, den = 0.f;
    for (int e = r0 + slot; e < r1; e += 4) {
        int s = ssrc[e];
        float v = als[s] + adh;
        v = LRELU(v);
        float p = __expf(v - mh);
        den += p;                      // identical across the 16 lanes of slot
        acc += feat[s * 16 + c] * p;
    }
    acc += __shfl_xor(acc, 16); acc += __shfl_xor(acc, 32);
    den += __shfl_xor(den, 16); den += __shfl_xor(den, 32);

    float v = acc / den + b2[c];
    float mm = v;
#pragma unroll
    for (int off = 8; off; off >>= 1) mm = fmaxf(mm, __shfl_xor(mm, off, 16));
    float ex = __expf(v - mm);
    float ssum = ex;
#pragma unroll
    for (int off = 8; off; off >>= 1) ssum += __shfl_xor(ssum, off, 16);
    if (lane < 16) out[n * 16 + c] = v - mm - logf(ssum);
}

// -------------------------- batchnorm ---------------------------------------
__global__ void bn_stats_k(const float* __restrict__ agg,
                           const float* __restrict__ b,
                           float* __restrict__ stats, int N) {
    int ch = threadIdx.x;             // 256
    int r0 = blockIdx.x * 64;
    int r1 = r0 + 64 < N ? r0 + 64 : N;
    float s = 0.f, s2 = 0.f;
    for (int r = r0; r < r1; r++) {
        float v = agg[r * 256 + ch] + b[ch];
        s += v; s2 += v * v;
    }
    atomicAdd(&stats[ch], s);
    atomicAdd(&stats[256 + ch], s2);
}

__global__ void bn_apply_k(const float* __restrict__ agg,
                           const float* __restrict__ b,
                           const float* __restrict__ stats,
                           const float* __restrict__ g,
                           const float* __restrict__ be,
                           float* __restrict__ outp, int N) {
    int gid = blockIdx.x * 256 + threadIdx.x;
    if (gid >= N * 256) return;
    int ch = gid & 255;
    float invN = 1.f / (float)N;
    float mu = stats[ch] * invN;
    float var = stats[256 + ch] * invN - mu * mu;
    float v = (agg[gid] + b[ch] - mu) * rsqrtf(var + 1e-5f) * g[ch] + be[ch];
    outp[gid] = v > 0.f ? v : 0.f;
}

// ---------------------------------------------------------------------------
extern "C" void kernel_launch(void* const* d_in, const int* in_sizes, int n_in,
                              void* d_out, int out_size, void* d_ws, size_t ws_size,
                              hipStream_t stream) {
    const float* x   = (const float*)d_in[0];
    const int*   ei  = (const int*)d_in[1];
    const float* W0  = (const float*)d_in[2];
    const float* as0 = (const float*)d_in[3];
    const float* ad0 = (const float*)d_in[4];
    const float* b0  = (const float*)d_in[5];
    const float* g0  = (const float*)d_in[6];
    const float* be0 = (const float*)d_in[7];
    const float* W1  = (const float*)d_in[8];
    const float* as1 = (const float*)d_in[9];
    const float* ad1 = (const float*)d_in[10];
    const float* b1  = (const float*)d_in[11];
    const float* g1  = (const float*)d_in[12];
    const float* be1 = (const float*)d_in[13];
    const float* W2  = (const float*)d_in[14];
    const float* as2 = (const float*)d_in[15];
    const float* ad2 = (const float*)d_in[16];
    const float* b2  = (const float*)d_in[17];
    float* out = (float*)d_out;

    const int N = in_sizes[0] / 128;       // 20000
    const int E = in_sizes[1] / 2;         // 320000
    const int ET = E + N;                  // with self loops

    float* ws = (float*)d_ws;
    size_t o = 0;
    float* hbuf = ws + o;  o += (size_t)N * 256;
    float* bufB = ws + o;  o += (size_t)N * 256;
    float* als  = ws + o;  o += (size_t)N * 8;
    float* ald  = ws + o;  o += (size_t)N * 8;
    float* stats = ws + o; o += 512;
    float* h2   = ws + o;  o += (size_t)N * 16;
    float* als2 = ws + o;  o += (size_t)N;
    float* ald2 = ws + o;  o += (size_t)N;
    int* deg    = (int*)(ws + o); o += (size_t)N;
    int* rowptr = (int*)(ws + o); o += (size_t)N + 1;
    int* cnt    = (int*)(ws + o); o += (size_t)N;
    int* ssrc   = (int*)(ws + o); o += (size_t)ET;

    const int gRows = (N + 31) / 32;
    const int gE    = (ET + 255) / 256;
    const int gN256 = (N * 256 + 255) / 256;
    const int gBN   = (N + 63) / 64;
    const int gWave = (N + 3) / 4;         // 1 wave per node, 4 waves/block

    // ---------------- CSR build (dst-sorted) ----------------
    fill_u32_k<<<(N + 255) / 256, 256, 0, stream>>>((unsigned*)deg, 0u, N);
    hist_k<<<gE, 256, 0, stream>>>(ei, E, N, deg);
    scan_k<<<1, 256, 0, stream>>>(deg, rowptr, cnt, N);
    scatter_k<<<gE, 256, 0, stream>>>(ei, E, N, cnt, ssrc);

    // ---------------- Layer 0 ----------------
    gemm_k<128, 256><<<gRows, 256, 0, stream>>>(x, W0, hbuf, N);
    logits8_k<<<N, 256, 0, stream>>>(hbuf, as0, ad0, als, ald, N);
    agg8_csr_k<<<gWave, 256, 0, stream>>>(rowptr, ssrc, als, ald, hbuf, bufB, N);
    fill_u32_k<<<2, 256, 0, stream>>>((unsigned*)stats, 0u, 512);
    bn_stats_k<<<gBN, 256, 0, stream>>>(bufB, b0, stats, N);
    bn_apply_k<<<gN256, 256, 0, stream>>>(bufB, b0, stats, g0, be0, hbuf, N);

    // ---------------- Layer 1 ----------------
    gemm_k<256, 256><<<gRows, 256, 0, stream>>>(hbuf, W1, bufB, N);
    logits8_k<<<N, 256, 0, stream>>>(bufB, as1, ad1, als, ald, N);
    agg8_csr_k<<<gWave, 256, 0, stream>>>(rowptr, ssrc, als, ald, bufB, hbuf, N);
    fill_u32_k<<<2, 256, 0, stream>>>((unsigned*)stats, 0u, 512);
    bn_stats_k<<<gBN, 256, 0, stream>>>(hbuf, b1, stats, N);
    bn_apply_k<<<gN256, 256, 0, stream>>>(hbuf, b1, stats, g1, be1, bufB, N);

    // ---------------- Layer 2 ----------------
    gemm_k<256, 16><<<gRows, 256, 0, stream>>>(bufB, W2, h2, N);
    logits1_k<<<(N + 15) / 16, 256, 0, stream>>>(h2, as2, ad2, als2, ald2, N);
    agg1_ls_k<<<gWave, 256, 0, stream>>>(rowptr, ssrc, als2, ald2, h2, b2, out, N);
}

// Round 3
// 400.073 us; speedup vs baseline: 2.4900x; 1.3049x over previous
//
#include <hip/hip_runtime.h>
#include <hip/hip_bf16.h>
#include <math.h>

// ---------------------------------------------------------------------------
// GAT 3-layer forward. N=20000 nodes, E=320000 edges (+N self loops).
// Round 3: register-tiled 64x64 GEMM (4x4 acc/thread) with fused attention
// logit epilogue (block owns exactly 2 heads). CSR gather-reduce aggregation.
// ---------------------------------------------------------------------------

#define LRELU(v) ((v) > 0.f ? (v) : 0.2f * (v))

// -------------------------- fills ------------------------------------------
__global__ void fill_u32_k(unsigned* p, unsigned v, int n) {
    int i = blockIdx.x * 256 + threadIdx.x;
    if (i < n) p[i] = v;
}

// -------------------------- CSR build --------------------------------------
__global__ void hist_k(const int* __restrict__ ei, int E, int N,
                       int* __restrict__ deg) {
    int e = blockIdx.x * 256 + threadIdx.x;
    if (e >= E + N) return;
    int d = (e < E) ? ei[E + e] : (e - E);
    atomicAdd(&deg[d], 1);
}

// single block, 256 threads: exclusive scan of deg -> rowptr, cnt
__global__ void scan_k(const int* __restrict__ deg, int* __restrict__ rowptr,
                       int* __restrict__ cnt, int N) {
    __shared__ int part[256];
    int tid = threadIdx.x;
    int chunk = (N + 255) >> 8;
    int b = tid * chunk;
    int e = b + chunk < N ? b + chunk : N;
    int s = 0;
    for (int i = b; i < e; i++) s += deg[i];
    part[tid] = s;
    __syncthreads();
    for (int d = 1; d < 256; d <<= 1) {
        int v = (tid >= d) ? part[tid - d] : 0;
        __syncthreads();
        part[tid] += v;
        __syncthreads();
    }
    int prefix = (tid == 0) ? 0 : part[tid - 1];
    for (int i = b; i < e; i++) {
        rowptr[i] = prefix;
        cnt[i] = prefix;
        prefix += deg[i];
    }
    if (tid == 255) rowptr[N] = prefix;
}

__global__ void scatter_k(const int* __restrict__ ei, int E, int N,
                          int* __restrict__ cnt, int* __restrict__ ssrc) {
    int e = blockIdx.x * 256 + threadIdx.x;
    if (e >= E + N) return;
    int s, d;
    if (e < E) { s = ei[e]; d = ei[E + e]; }
    else       { s = d = e - E; }
    int pos = atomicAdd(&cnt[d], 1);
    ssrc[pos] = s;
}

// ------------- tiled GEMM (OUT=256) + fused per-node logits -----------------
// 64x64 tile, BK=32, 256 threads, 4x4 acc. Block (bx,by) covers rows
// bx*64..+63 and cols by*64..+63 == heads {2by, 2by+1} completely, so the
// attention logits als/ald for those heads are reduced in the epilogue.
template <int IN>
__global__ __launch_bounds__(256) void gemm64_k(
        const float* __restrict__ X, const float* __restrict__ W,
        const float* __restrict__ as, const float* __restrict__ ad,
        float* __restrict__ Y, float* __restrict__ als, float* __restrict__ ald,
        int M) {
    constexpr int BM = 64, BN = 64, BK = 32, OUT = 256;
    __shared__ float Xs[BK][BM + 4];
    __shared__ float Ws[BK][BN + 4];
    const int tid = threadIdx.x;
    const int tx = tid & 15, ty = tid >> 4;
    const int row0 = blockIdx.x * BM, col0 = blockIdx.y * BN;
    const int lr = tid >> 2;           // X-load row 0..63
    const int lk = (tid & 3) * 8;      // X-load k offset {0,8,16,24}
    const int wr = tid >> 3;           // W-load k row 0..31
    const int wc = (tid & 7) * 8;      // W-load col offset {0..56}
    float acc[4][4] = {};
    for (int k0 = 0; k0 < IN; k0 += BK) {
        float4 xa = {0, 0, 0, 0}, xb = {0, 0, 0, 0};
        if (row0 + lr < M) {
            const float* xp = X + (size_t)(row0 + lr) * IN + k0 + lk;
            xa = *(const float4*)xp;
            xb = *(const float4*)(xp + 4);
        }
        const float* wp = W + (size_t)(k0 + wr) * OUT + col0 + wc;
        float4 wa = *(const float4*)wp;
        float4 wb = *(const float4*)(wp + 4);
        __syncthreads();
        Xs[lk + 0][lr] = xa.x; Xs[lk + 1][lr] = xa.y;
        Xs[lk + 2][lr] = xa.z; Xs[lk + 3][lr] = xa.w;
        Xs[lk + 4][lr] = xb.x; Xs[lk + 5][lr] = xb.y;
        Xs[lk + 6][lr] = xb.z; Xs[lk + 7][lr] = xb.w;
        *(float4*)&Ws[wr][wc] = wa;
        *(float4*)&Ws[wr][wc + 4] = wb;
        __syncthreads();
#pragma unroll
        for (int k = 0; k < BK; k++) {
            float4 a = *(const float4*)&Xs[k][ty * 4];
            float4 b = *(const float4*)&Ws[k][tx * 4];
            acc[0][0] += a.x * b.x; acc[0][1] += a.x * b.y;
            acc[0][2] += a.x * b.z; acc[0][3] += a.x * b.w;
            acc[1][0] += a.y * b.x; acc[1][1] += a.y * b.y;
            acc[1][2] += a.y * b.z; acc[1][3] += a.y * b.w;
            acc[2][0] += a.z * b.x; acc[2][1] += a.z * b.y;
            acc[2][2] += a.z * b.z; acc[2][3] += a.z * b.w;
            acc[3][0] += a.w * b.x; acc[3][1] += a.w * b.y;
            acc[3][2] += a.w * b.z; acc[3][3] += a.w * b.w;
        }
    }
    // Y store
#pragma unroll
    for (int i = 0; i < 4; i++) {
        int r = row0 + ty * 4 + i;
        if (r < M) {
            float4 v = {acc[i][0], acc[i][1], acc[i][2], acc[i][3]};
            *(float4*)(Y + (size_t)r * OUT + col0 + tx * 4) = v;
        }
    }
    // fused logits: head owned by this thread's columns
    const int h = 2 * blockIdx.y + (tx >> 3);
    const int cmod = (tx * 4) & 31;
    float4 a4 = *(const float4*)(as + h * 32 + cmod);
    float4 d4 = *(const float4*)(ad + h * 32 + cmod);
#pragma unroll
    for (int i = 0; i < 4; i++) {
        float ps = acc[i][0] * a4.x + acc[i][1] * a4.y +
                   acc[i][2] * a4.z + acc[i][3] * a4.w;
        float pd = acc[i][0] * d4.x + acc[i][1] * d4.y +
                   acc[i][2] * d4.z + acc[i][3] * d4.w;
        ps += __shfl_xor(ps, 1); ps += __shfl_xor(ps, 2); ps += __shfl_xor(ps, 4);
        pd += __shfl_xor(pd, 1); pd += __shfl_xor(pd, 2); pd += __shfl_xor(pd, 4);
        int r = row0 + ty * 4 + i;
        if ((tx & 7) == 0 && r < M) {
            als[r * 8 + h] = ps;
            ald[r * 8 + h] = pd;
        }
    }
}

// -------------------------- small GEMM (L2): Y = X @ W, OUT=16 --------------
template <int IN, int OUT>
__global__ void gemm_k(const float* __restrict__ X, const float* __restrict__ W,
                       float* __restrict__ Y, int M) {
    constexpr int ROWS = 32;
    constexpr int GROUPS = 256 / OUT;
    constexpr int RPT = ROWS / (GROUPS ? GROUPS : 1);
    __shared__ float xs[ROWS][IN];
    const int row0 = blockIdx.x * ROWS;
    const int tid = threadIdx.x;
    for (int idx = tid; idx < ROWS * IN; idx += 256) {
        int r = idx / IN, k = idx % IN;
        int gr = row0 + r;
        xs[r][k] = (gr < M) ? X[gr * IN + k] : 0.f;
    }
    __syncthreads();
    const int j = tid % OUT;
    const int rbase = (tid / OUT) * RPT;
    float acc[RPT];
#pragma unroll
    for (int r = 0; r < RPT; r++) acc[r] = 0.f;
    for (int k = 0; k < IN; k++) {
        float w = W[k * OUT + j];
#pragma unroll
        for (int r = 0; r < RPT; r++) acc[r] += xs[rbase + r][k] * w;
    }
#pragma unroll
    for (int r = 0; r < RPT; r++) {
        int gr = row0 + rbase + r;
        if (gr < M) Y[gr * OUT + j] = acc[r];
    }
}

// H=1 C=16 logits: one block handles 16 nodes
__global__ void logits1_k(const float* __restrict__ feat,
                          const float* __restrict__ as,
                          const float* __restrict__ ad,
                          float* __restrict__ als, float* __restrict__ ald,
                          int N) {
    int tid = threadIdx.x;
    int n = blockIdx.x * 16 + (tid >> 4);
    int c = tid & 15;
    if (n >= N) return;
    float v = feat[n * 16 + c];
    float ps = v * as[c], pd = v * ad[c];
    for (int off = 8; off; off >>= 1) {
        ps += __shfl_xor(ps, off, 16);
        pd += __shfl_xor(pd, off, 16);
    }
    if (c == 0) { als[n] = ps; ald[n] = pd; }
}

// -------------------------- CSR aggregate, H=8 C=32 -------------------------
__global__ void agg8_csr_k(const int* __restrict__ rowptr,
                           const int* __restrict__ ssrc,
                           const float* __restrict__ als,
                           const float* __restrict__ ald,
                           const float* __restrict__ feat,
                           float* __restrict__ agg, int N) {
    int lane = threadIdx.x & 63;
    int n = blockIdx.x * 4 + (threadIdx.x >> 6);
    if (n >= N) return;
    const int r0 = rowptr[n], r1 = rowptr[n + 1];
    const int h0 = lane >> 3;          // head owned by this lane (pass 1)
    const int c0 = lane << 2;          // 4 channels owned in pass 2
    const int hc = c0 >> 5;            // head of the owned channels
    float adh = ald[n * 8 + h0];
    float adc = ald[n * 8 + hc];

    float mh = -1e30f;
    for (int e = r0; e < r1; e++) {
        int s = ssrc[e];               // wave-uniform -> broadcast load
        float v = als[s * 8 + h0] + adh;
        mh = fmaxf(mh, LRELU(v));
    }
    float mc = __shfl(mh, hc << 3);

    float4 acc = {0.f, 0.f, 0.f, 0.f};
    float den = 0.f;
    for (int e = r0; e < r1; e++) {
        int s = ssrc[e];
        float v = als[s * 8 + hc] + adc;
        v = LRELU(v);
        float p = __expf(v - mc);
        den += p;
        float4 f = *reinterpret_cast<const float4*>(feat + (size_t)s * 256 + c0);
        acc.x += f.x * p; acc.y += f.y * p; acc.z += f.z * p; acc.w += f.w * p;
    }
    float inv = 1.f / den;
    acc.x *= inv; acc.y *= inv; acc.z *= inv; acc.w *= inv;
    *reinterpret_cast<float4*>(agg + (size_t)n * 256 + c0) = acc;
}

// -------------------------- CSR aggregate + log_softmax, H=1 C=16 -----------
__global__ void agg1_ls_k(const int* __restrict__ rowptr,
                          const int* __restrict__ ssrc,
                          const float* __restrict__ als,
                          const float* __restrict__ ald,
                          const float* __restrict__ feat,
                          const float* __restrict__ b2,
                          float* __restrict__ out, int N) {
    int lane = threadIdx.x & 63;
    int n = blockIdx.x * 4 + (threadIdx.x >> 6);
    if (n >= N) return;
    const int r0 = rowptr[n], r1 = rowptr[n + 1];
    float adh = ald[n];

    float mh = -1e30f;
    for (int e = r0 + lane; e < r1; e += 64) {
        int s = ssrc[e];
        float v = als[s] + adh;
        mh = fmaxf(mh, LRELU(v));
    }
#pragma unroll
    for (int off = 32; off; off >>= 1) mh = fmaxf(mh, __shfl_xor(mh, off));

    int slot = lane >> 4, c = lane & 15;
    float acc = 0.f, den = 0.f;
    for (int e = r0 + slot; e < r1; e += 4) {
        int s = ssrc[e];
        float v = als[s] + adh;
        v = LRELU(v);
        float p = __expf(v - mh);
        den += p;
        acc += feat[s * 16 + c] * p;
    }
    acc += __shfl_xor(acc, 16); acc += __shfl_xor(acc, 32);
    den += __shfl_xor(den, 16); den += __shfl_xor(den, 32);

    float v = acc / den + b2[c];
    float mm = v;
#pragma unroll
    for (int off = 8; off; off >>= 1) mm = fmaxf(mm, __shfl_xor(mm, off, 16));
    float ex = __expf(v - mm);
    float ssum = ex;
#pragma unroll
    for (int off = 8; off; off >>= 1) ssum += __shfl_xor(ssum, off, 16);
    if (lane < 16) out[n * 16 + c] = v - mm - logf(ssum);
}

// -------------------------- batchnorm ---------------------------------------
__global__ void bn_stats_k(const float* __restrict__ agg,
                           const float* __restrict__ b,
                           float* __restrict__ stats, int N) {
    int ch = threadIdx.x;             // 256
    int r0 = blockIdx.x * 64;
    int r1 = r0 + 64 < N ? r0 + 64 : N;
    float s = 0.f, s2 = 0.f;
    for (int r = r0; r < r1; r++) {
        float v = agg[r * 256 + ch] + b[ch];
        s += v; s2 += v * v;
    }
    atomicAdd(&stats[ch], s);
    atomicAdd(&stats[256 + ch], s2);
}

__global__ void bn_apply_k(const float* __restrict__ agg,
                           const float* __restrict__ b,
                           const float* __restrict__ stats,
                           const float* __restrict__ g,
                           const float* __restrict__ be,
                           float* __restrict__ outp, int N) {
    int gid = blockIdx.x * 256 + threadIdx.x;
    if (gid >= N * 256) return;
    int ch = gid & 255;
    float invN = 1.f / (float)N;
    float mu = stats[ch] * invN;
    float var = stats[256 + ch] * invN - mu * mu;
    float v = (agg[gid] + b[ch] - mu) * rsqrtf(var + 1e-5f) * g[ch] + be[ch];
    outp[gid] = v > 0.f ? v : 0.f;
}

// ---------------------------------------------------------------------------
extern "C" void kernel_launch(void* const* d_in, const int* in_sizes, int n_in,
                              void* d_out, int out_size, void* d_ws, size_t ws_size,
                              hipStream_t stream) {
    const float* x   = (const float*)d_in[0];
    const int*   ei  = (const int*)d_in[1];
    const float* W0  = (const float*)d_in[2];
    const float* as0 = (const float*)d_in[3];
    const float* ad0 = (const float*)d_in[4];
    const float* b0  = (const float*)d_in[5];
    const float* g0  = (const float*)d_in[6];
    const float* be0 = (const float*)d_in[7];
    const float* W1  = (const float*)d_in[8];
    const float* as1 = (const float*)d_in[9];
    const float* ad1 = (const float*)d_in[10];
    const float* b1  = (const float*)d_in[11];
    const float* g1  = (const float*)d_in[12];
    const float* be1 = (const float*)d_in[13];
    const float* W2  = (const float*)d_in[14];
    const float* as2 = (const float*)d_in[15];
    const float* ad2 = (const float*)d_in[16];
    const float* b2  = (const float*)d_in[17];
    float* out = (float*)d_out;

    const int N = in_sizes[0] / 128;       // 20000
    const int E = in_sizes[1] / 2;         // 320000
    const int ET = E + N;                  // with self loops

    float* ws = (float*)d_ws;
    size_t o = 0;
    float* hbuf = ws + o;  o += (size_t)N * 256;
    float* bufB = ws + o;  o += (size_t)N * 256;
    float* als  = ws + o;  o += (size_t)N * 8;
    float* ald  = ws + o;  o += (size_t)N * 8;
    float* stats = ws + o; o += 512;
    float* h2   = ws + o;  o += (size_t)N * 16;
    float* als2 = ws + o;  o += (size_t)N;
    float* ald2 = ws + o;  o += (size_t)N;
    int* deg    = (int*)(ws + o); o += (size_t)N;
    int* rowptr = (int*)(ws + o); o += (size_t)N + 1;
    int* cnt    = (int*)(ws + o); o += (size_t)N;
    int* ssrc   = (int*)(ws + o); o += (size_t)ET;

    const int gE    = (ET + 255) / 256;
    const int gN256 = (N * 256 + 255) / 256;
    const int gBN   = (N + 63) / 64;
    const int gWave = (N + 3) / 4;         // 1 wave per node, 4 waves/block
    dim3 gGemm((N + 63) / 64, 4);

    // ---------------- CSR build (dst-sorted) ----------------
    fill_u32_k<<<(N + 255) / 256, 256, 0, stream>>>((unsigned*)deg, 0u, N);
    hist_k<<<gE, 256, 0, stream>>>(ei, E, N, deg);
    scan_k<<<1, 256, 0, stream>>>(deg, rowptr, cnt, N);
    scatter_k<<<gE, 256, 0, stream>>>(ei, E, N, cnt, ssrc);

    // ---------------- Layer 0 ----------------
    gemm64_k<128><<<gGemm, 256, 0, stream>>>(x, W0, as0, ad0, hbuf, als, ald, N);
    agg8_csr_k<<<gWave, 256, 0, stream>>>(rowptr, ssrc, als, ald, hbuf, bufB, N);
    fill_u32_k<<<2, 256, 0, stream>>>((unsigned*)stats, 0u, 512);
    bn_stats_k<<<gBN, 256, 0, stream>>>(bufB, b0, stats, N);
    bn_apply_k<<<gN256, 256, 0, stream>>>(bufB, b0, stats, g0, be0, hbuf, N);

    // ---------------- Layer 1 ----------------
    gemm64_k<256><<<gGemm, 256, 0, stream>>>(hbuf, W1, as1, ad1, bufB, als, ald, N);
    agg8_csr_k<<<gWave, 256, 0, stream>>>(rowptr, ssrc, als, ald, bufB, hbuf, N);
    fill_u32_k<<<2, 256, 0, stream>>>((unsigned*)stats, 0u, 512);
    bn_stats_k<<<gBN, 256, 0, stream>>>(hbuf, b1, stats, N);
    bn_apply_k<<<gN256, 256, 0, stream>>>(hbuf, b1, stats, g1, be1, bufB, N);

    // ---------------- Layer 2 ----------------
    gemm_k<256, 16><<<(N + 31) / 32, 256, 0, stream>>>(bufB, W2, h2, N);
    logits1_k<<<(N + 15) / 16, 256, 0, stream>>>(h2, as2, ad2, als2, ald2, N);
    agg1_ls_k<<<gWave, 256, 0, stream>>>(rowptr, ssrc, als2, ald2, h2, b2, out, N);
}

// Round 4
// 345.613 us; speedup vs baseline: 2.8823x; 1.1576x over previous
//
#include <hip/hip_runtime.h>
#include <hip/hip_bf16.h>
#include <math.h>

// ---------------------------------------------------------------------------
// GAT 3-layer forward. N=20000 nodes, E=320000 edges (+N self loops).
// Round 4: bf16 feature table for the edge gather (half the bytes), half-wave
// per edge (2 edges in flight per wave). GEMM writes bf16 directly; BN apply
// in place. CSR gather-reduce, no fp atomics in hot path.
// ---------------------------------------------------------------------------

#define LRELU(v) ((v) > 0.f ? (v) : 0.2f * (v))

__device__ __forceinline__ unsigned short f2b(float f) {
    unsigned u = __float_as_uint(f);
    unsigned r = (u + 0x7fffu + ((u >> 16) & 1u)) >> 16;   // RNE
    return (unsigned short)r;
}
__device__ __forceinline__ float bl(unsigned u) { return __uint_as_float(u << 16); }
__device__ __forceinline__ float bh(unsigned u) { return __uint_as_float(u & 0xffff0000u); }

// -------------------------- fills ------------------------------------------
__global__ void fill_u32_k(unsigned* p, unsigned v, int n) {
    int i = blockIdx.x * 256 + threadIdx.x;
    if (i < n) p[i] = v;
}

// -------------------------- CSR build --------------------------------------
__global__ void hist_k(const int* __restrict__ ei, int E, int N,
                       int* __restrict__ deg) {
    int e = blockIdx.x * 256 + threadIdx.x;
    if (e >= E + N) return;
    int d = (e < E) ? ei[E + e] : (e - E);
    atomicAdd(&deg[d], 1);
}

// single block, 256 threads: exclusive scan of deg -> rowptr, cnt
__global__ void scan_k(const int* __restrict__ deg, int* __restrict__ rowptr,
                       int* __restrict__ cnt, int N) {
    __shared__ int part[256];
    int tid = threadIdx.x;
    int chunk = (N + 255) >> 8;
    int b = tid * chunk;
    int e = b + chunk < N ? b + chunk : N;
    int s = 0;
    for (int i = b; i < e; i++) s += deg[i];
    part[tid] = s;
    __syncthreads();
    for (int d = 1; d < 256; d <<= 1) {
        int v = (tid >= d) ? part[tid - d] : 0;
        __syncthreads();
        part[tid] += v;
        __syncthreads();
    }
    int prefix = (tid == 0) ? 0 : part[tid - 1];
    for (int i = b; i < e; i++) {
        rowptr[i] = prefix;
        cnt[i] = prefix;
        prefix += deg[i];
    }
    if (tid == 255) rowptr[N] = prefix;
}

__global__ void scatter_k(const int* __restrict__ ei, int E, int N,
                          int* __restrict__ cnt, int* __restrict__ ssrc) {
    int e = blockIdx.x * 256 + threadIdx.x;
    if (e >= E + N) return;
    int s, d;
    if (e < E) { s = ei[e]; d = ei[E + e]; }
    else       { s = d = e - E; }
    int pos = atomicAdd(&cnt[d], 1);
    ssrc[pos] = s;
}

// ------------- tiled GEMM (OUT=256) + fused per-node logits -----------------
// 64x64 tile, BK=32, 256 threads, 4x4 acc. Block (bx,by) covers heads
// {2by, 2by+1} completely -> logits reduced in epilogue. Y written as bf16
// (only consumer is the edge gather).
template <int IN>
__global__ __launch_bounds__(256) void gemm64_k(
        const float* __restrict__ X, const float* __restrict__ W,
        const float* __restrict__ as, const float* __restrict__ ad,
        __hip_bfloat16* __restrict__ Y,
        float* __restrict__ als, float* __restrict__ ald, int M) {
    constexpr int BM = 64, BN = 64, BK = 32, OUT = 256;
    __shared__ float Xs[BK][BM + 4];
    __shared__ float Ws[BK][BN + 4];
    const int tid = threadIdx.x;
    const int tx = tid & 15, ty = tid >> 4;
    const int row0 = blockIdx.x * BM, col0 = blockIdx.y * BN;
    const int lr = tid >> 2;           // X-load row 0..63
    const int lk = (tid & 3) * 8;      // X-load k offset {0,8,16,24}
    const int wr = tid >> 3;           // W-load k row 0..31
    const int wc = (tid & 7) * 8;      // W-load col offset {0..56}
    float acc[4][4] = {};
    for (int k0 = 0; k0 < IN; k0 += BK) {
        float4 xa = {0, 0, 0, 0}, xb = {0, 0, 0, 0};
        if (row0 + lr < M) {
            const float* xp = X + (size_t)(row0 + lr) * IN + k0 + lk;
            xa = *(const float4*)xp;
            xb = *(const float4*)(xp + 4);
        }
        const float* wp = W + (size_t)(k0 + wr) * OUT + col0 + wc;
        float4 wa = *(const float4*)wp;
        float4 wb = *(const float4*)(wp + 4);
        __syncthreads();
        Xs[lk + 0][lr] = xa.x; Xs[lk + 1][lr] = xa.y;
        Xs[lk + 2][lr] = xa.z; Xs[lk + 3][lr] = xa.w;
        Xs[lk + 4][lr] = xb.x; Xs[lk + 5][lr] = xb.y;
        Xs[lk + 6][lr] = xb.z; Xs[lk + 7][lr] = xb.w;
        *(float4*)&Ws[wr][wc] = wa;
        *(float4*)&Ws[wr][wc + 4] = wb;
        __syncthreads();
#pragma unroll
        for (int k = 0; k < BK; k++) {
            float4 a = *(const float4*)&Xs[k][ty * 4];
            float4 b = *(const float4*)&Ws[k][tx * 4];
            acc[0][0] += a.x * b.x; acc[0][1] += a.x * b.y;
            acc[0][2] += a.x * b.z; acc[0][3] += a.x * b.w;
            acc[1][0] += a.y * b.x; acc[1][1] += a.y * b.y;
            acc[1][2] += a.y * b.z; acc[1][3] += a.y * b.w;
            acc[2][0] += a.z * b.x; acc[2][1] += a.z * b.y;
            acc[2][2] += a.z * b.z; acc[2][3] += a.z * b.w;
            acc[3][0] += a.w * b.x; acc[3][1] += a.w * b.y;
            acc[3][2] += a.w * b.z; acc[3][3] += a.w * b.w;
        }
    }
    // Y store (bf16)
#pragma unroll
    for (int i = 0; i < 4; i++) {
        int r = row0 + ty * 4 + i;
        if (r < M) {
            ushort4 v;
            v.x = f2b(acc[i][0]); v.y = f2b(acc[i][1]);
            v.z = f2b(acc[i][2]); v.w = f2b(acc[i][3]);
            *(ushort4*)((unsigned short*)Y + (size_t)r * OUT + col0 + tx * 4) = v;
        }
    }
    // fused logits: head owned by this thread's columns
    const int h = 2 * blockIdx.y + (tx >> 3);
    const int cmod = (tx * 4) & 31;
    float4 a4 = *(const float4*)(as + h * 32 + cmod);
    float4 d4 = *(const float4*)(ad + h * 32 + cmod);
#pragma unroll
    for (int i = 0; i < 4; i++) {
        float ps = acc[i][0] * a4.x + acc[i][1] * a4.y +
                   acc[i][2] * a4.z + acc[i][3] * a4.w;
        float pd = acc[i][0] * d4.x + acc[i][1] * d4.y +
                   acc[i][2] * d4.z + acc[i][3] * d4.w;
        ps += __shfl_xor(ps, 1); ps += __shfl_xor(ps, 2); ps += __shfl_xor(ps, 4);
        pd += __shfl_xor(pd, 1); pd += __shfl_xor(pd, 2); pd += __shfl_xor(pd, 4);
        int r = row0 + ty * 4 + i;
        if ((tx & 7) == 0 && r < M) {
            als[r * 8 + h] = ps;
            ald[r * 8 + h] = pd;
        }
    }
}

// -------------------------- small GEMM (L2): Y = X @ W, OUT=16 --------------
template <int IN, int OUT>
__global__ void gemm_k(const float* __restrict__ X, const float* __restrict__ W,
                       float* __restrict__ Y, int M) {
    constexpr int ROWS = 32;
    constexpr int GROUPS = 256 / OUT;
    constexpr int RPT = ROWS / (GROUPS ? GROUPS : 1);
    __shared__ float xs[ROWS][IN];
    const int row0 = blockIdx.x * ROWS;
    const int tid = threadIdx.x;
    for (int idx = tid; idx < ROWS * IN; idx += 256) {
        int r = idx / IN, k = idx % IN;
        int gr = row0 + r;
        xs[r][k] = (gr < M) ? X[gr * IN + k] : 0.f;
    }
    __syncthreads();
    const int j = tid % OUT;
    const int rbase = (tid / OUT) * RPT;
    float acc[RPT];
#pragma unroll
    for (int r = 0; r < RPT; r++) acc[r] = 0.f;
    for (int k = 0; k < IN; k++) {
        float w = W[k * OUT + j];
#pragma unroll
        for (int r = 0; r < RPT; r++) acc[r] += xs[rbase + r][k] * w;
    }
#pragma unroll
    for (int r = 0; r < RPT; r++) {
        int gr = row0 + rbase + r;
        if (gr < M) Y[gr * OUT + j] = acc[r];
    }
}

// H=1 C=16 logits: one block handles 16 nodes
__global__ void logits1_k(const float* __restrict__ feat,
                          const float* __restrict__ as,
                          const float* __restrict__ ad,
                          float* __restrict__ als, float* __restrict__ ald,
                          int N) {
    int tid = threadIdx.x;
    int n = blockIdx.x * 16 + (tid >> 4);
    int c = tid & 15;
    if (n >= N) return;
    float v = feat[n * 16 + c];
    float ps = v * as[c], pd = v * ad[c];
    for (int off = 8; off; off >>= 1) {
        ps += __shfl_xor(ps, off, 16);
        pd += __shfl_xor(pd, off, 16);
    }
    if (c == 0) { als[n] = ps; ald[n] = pd; }
}

// -------------------------- CSR aggregate, H=8 C=32, bf16 feat --------------
// one wave per node; each half-wave (32 lanes) owns one edge per iteration.
// lane l = lane&31 owns 8 bf16 channels c0 = l*8 of head h = l>>2, which is
// also the head whose logit/max it tracks (no redistribution needed).
__global__ void agg8_csr_k(const int* __restrict__ rowptr,
                           const int* __restrict__ ssrc,
                           const float* __restrict__ als,
                           const float* __restrict__ ald,
                           const __hip_bfloat16* __restrict__ feat,
                           float* __restrict__ agg, int N) {
    int lane = threadIdx.x & 63;
    int n = blockIdx.x * 4 + (threadIdx.x >> 6);
    if (n >= N) return;
    const int r0 = rowptr[n], r1 = rowptr[n + 1];
    const int sub = lane >> 5;         // which edge of the pair
    const int l = lane & 31;
    const int h = l >> 2;              // head for max AND channels
    const int c0 = l * 8;              // 8 bf16 channels
    const float adh = ald[n * 8 + h];

    float mh = -1e30f;
    for (int e = r0 + sub; e < r1; e += 2) {
        int s = ssrc[e];
        float v = als[s * 8 + h] + adh;
        mh = fmaxf(mh, LRELU(v));
    }
    mh = fmaxf(mh, __shfl_xor(mh, 32));   // merge the two half-waves

    float acc[8] = {};
    float den = 0.f;
    const unsigned short* fp = (const unsigned short*)feat;
    for (int e = r0 + sub; e < r1; e += 2) {
        int s = ssrc[e];
        float v = als[s * 8 + h] + adh;
        v = LRELU(v);
        float p = __expf(v - mh);
        den += p;
        uint4 f = *(const uint4*)(fp + (size_t)s * 256 + c0);
        acc[0] += bl(f.x) * p; acc[1] += bh(f.x) * p;
        acc[2] += bl(f.y) * p; acc[3] += bh(f.y) * p;
        acc[4] += bl(f.z) * p; acc[5] += bh(f.z) * p;
        acc[6] += bl(f.w) * p; acc[7] += bh(f.w) * p;
    }
    den += __shfl_xor(den, 32);
#pragma unroll
    for (int j = 0; j < 8; j++) acc[j] += __shfl_xor(acc[j], 32);
    float inv = 1.f / den;
    float4 o0 = {acc[0] * inv, acc[1] * inv, acc[2] * inv, acc[3] * inv};
    float4 o1 = {acc[4] * inv, acc[5] * inv, acc[6] * inv, acc[7] * inv};
    float* op = agg + (size_t)n * 256 + c0;
    *(float4*)op = o0;
    *(float4*)(op + 4) = o1;
}

// -------------------------- CSR aggregate + log_softmax, H=1 C=16 -----------
__global__ void agg1_ls_k(const int* __restrict__ rowptr,
                          const int* __restrict__ ssrc,
                          const float* __restrict__ als,
                          const float* __restrict__ ald,
                          const float* __restrict__ feat,
                          const float* __restrict__ b2,
                          float* __restrict__ out, int N) {
    int lane = threadIdx.x & 63;
    int n = blockIdx.x * 4 + (threadIdx.x >> 6);
    if (n >= N) return;
    const int r0 = rowptr[n], r1 = rowptr[n + 1];
    float adh = ald[n];

    float mh = -1e30f;
    for (int e = r0 + lane; e < r1; e += 64) {
        int s = ssrc[e];
        float v = als[s] + adh;
        mh = fmaxf(mh, LRELU(v));
    }
#pragma unroll
    for (int off = 32; off; off >>= 1) mh = fmaxf(mh, __shfl_xor(mh, off));

    int slot = lane >> 4, c = lane & 15;
    float acc = 0.f, den = 0.f;
    for (int e = r0 + slot; e < r1; e += 4) {
        int s = ssrc[e];
        float v = als[s] + adh;
        v = LRELU(v);
        float p = __expf(v - mh);
        den += p;
        acc += feat[s * 16 + c] * p;
    }
    acc += __shfl_xor(acc, 16); acc += __shfl_xor(acc, 32);
    den += __shfl_xor(den, 16); den += __shfl_xor(den, 32);

    float v = acc / den + b2[c];
    float mm = v;
#pragma unroll
    for (int off = 8; off; off >>= 1) mm = fmaxf(mm, __shfl_xor(mm, off, 16));
    float ex = __expf(v - mm);
    float ssum = ex;
#pragma unroll
    for (int off = 8; off; off >>= 1) ssum += __shfl_xor(ssum, off, 16);
    if (lane < 16) out[n * 16 + c] = v - mm - logf(ssum);
}

// -------------------------- batchnorm ---------------------------------------
__global__ void bn_stats_k(const float* __restrict__ agg,
                           const float* __restrict__ b,
                           float* __restrict__ stats, int N) {
    int ch = threadIdx.x;             // 256
    int r0 = blockIdx.x * 64;
    int r1 = r0 + 64 < N ? r0 + 64 : N;
    float s = 0.f, s2 = 0.f;
    for (int r = r0; r < r1; r++) {
        float v = agg[r * 256 + ch] + b[ch];
        s += v; s2 += v * v;
    }
    atomicAdd(&stats[ch], s);
    atomicAdd(&stats[256 + ch], s2);
}

// in-place safe (each thread reads/writes its own element)
__global__ void bn_apply_k(const float* __restrict__ agg,
                           const float* __restrict__ b,
                           const float* __restrict__ stats,
                           const float* __restrict__ g,
                           const float* __restrict__ be,
                           float* __restrict__ outp, int N) {
    int gid = blockIdx.x * 256 + threadIdx.x;
    if (gid >= N * 256) return;
    int ch = gid & 255;
    float invN = 1.f / (float)N;
    float mu = stats[ch] * invN;
    float var = stats[256 + ch] * invN - mu * mu;
    float v = (agg[gid] + b[ch] - mu) * rsqrtf(var + 1e-5f) * g[ch] + be[ch];
    outp[gid] = v > 0.f ? v : 0.f;
}

// ---------------------------------------------------------------------------
extern "C" void kernel_launch(void* const* d_in, const int* in_sizes, int n_in,
                              void* d_out, int out_size, void* d_ws, size_t ws_size,
                              hipStream_t stream) {
    const float* x   = (const float*)d_in[0];
    const int*   ei  = (const int*)d_in[1];
    const float* W0  = (const float*)d_in[2];
    const float* as0 = (const float*)d_in[3];
    const float* ad0 = (const float*)d_in[4];
    const float* b0  = (const float*)d_in[5];
    const float* g0  = (const float*)d_in[6];
    const float* be0 = (const float*)d_in[7];
    const float* W1  = (const float*)d_in[8];
    const float* as1 = (const float*)d_in[9];
    const float* ad1 = (const float*)d_in[10];
    const float* b1  = (const float*)d_in[11];
    const float* g1  = (const float*)d_in[12];
    const float* be1 = (const float*)d_in[13];
    const float* W2  = (const float*)d_in[14];
    const float* as2 = (const float*)d_in[15];
    const float* ad2 = (const float*)d_in[16];
    const float* b2  = (const float*)d_in[17];
    float* out = (float*)d_out;

    const int N = in_sizes[0] / 128;       // 20000
    const int E = in_sizes[1] / 2;         // 320000
    const int ET = E + N;                  // with self loops

    float* ws = (float*)d_ws;
    size_t o = 0;
    float* aggA = ws + o;  o += (size_t)N * 256;   // agg out / BN in-place / gemm in
    __hip_bfloat16* hb16 = (__hip_bfloat16*)(ws + o); o += (size_t)N * 128; // bf16 feat
    float* als  = ws + o;  o += (size_t)N * 8;
    float* ald  = ws + o;  o += (size_t)N * 8;
    float* stats = ws + o; o += 512;
    float* h2   = ws + o;  o += (size_t)N * 16;
    float* als2 = ws + o;  o += (size_t)N;
    float* ald2 = ws + o;  o += (size_t)N;
    int* deg    = (int*)(ws + o); o += (size_t)N;
    int* rowptr = (int*)(ws + o); o += (size_t)N + 1;
    int* cnt    = (int*)(ws + o); o += (size_t)N;
    int* ssrc   = (int*)(ws + o); o += (size_t)ET;

    const int gE    = (ET + 255) / 256;
    const int gN256 = (N * 256 + 255) / 256;
    const int gBN   = (N + 63) / 64;
    const int gWave = (N + 3) / 4;         // 1 wave per node, 4 waves/block
    dim3 gGemm((N + 63) / 64, 4);

    // ---------------- CSR build (dst-sorted) ----------------
    fill_u32_k<<<(N + 255) / 256, 256, 0, stream>>>((unsigned*)deg, 0u, N);
    hist_k<<<gE, 256, 0, stream>>>(ei, E, N, deg);
    scan_k<<<1, 256, 0, stream>>>(deg, rowptr, cnt, N);
    scatter_k<<<gE, 256, 0, stream>>>(ei, E, N, cnt, ssrc);

    // ---------------- Layer 0 ----------------
    gemm64_k<128><<<gGemm, 256, 0, stream>>>(x, W0, as0, ad0, hb16, als, ald, N);
    agg8_csr_k<<<gWave, 256, 0, stream>>>(rowptr, ssrc, als, ald, hb16, aggA, N);
    fill_u32_k<<<2, 256, 0, stream>>>((unsigned*)stats, 0u, 512);
    bn_stats_k<<<gBN, 256, 0, stream>>>(aggA, b0, stats, N);
    bn_apply_k<<<gN256, 256, 0, stream>>>(aggA, b0, stats, g0, be0, aggA, N);

    // ---------------- Layer 1 ----------------
    gemm64_k<256><<<gGemm, 256, 0, stream>>>(aggA, W1, as1, ad1, hb16, als, ald, N);
    agg8_csr_k<<<gWave, 256, 0, stream>>>(rowptr, ssrc, als, ald, hb16, aggA, N);
    fill_u32_k<<<2, 256, 0, stream>>>((unsigned*)stats, 0u, 512);
    bn_stats_k<<<gBN, 256, 0, stream>>>(aggA, b1, stats, N);
    bn_apply_k<<<gN256, 256, 0, stream>>>(aggA, b1, stats, g1, be1, aggA, N);

    // ---------------- Layer 2 ----------------
    gemm_k<256, 16><<<(N + 31) / 32, 256, 0, stream>>>(aggA, W2, h2, N);
    logits1_k<<<(N + 15) / 16, 256, 0, stream>>>(h2, as2, ad2, als2, ald2, N);
    agg1_ls_k<<<gWave, 256, 0, stream>>>(rowptr, ssrc, als2, ald2, h2, b2, out, N);
}

// Round 5
// 305.524 us; speedup vs baseline: 3.2605x; 1.1312x over previous
//
#include <hip/hip_runtime.h>
#include <hip/hip_bf16.h>
#include <math.h>

// ---------------------------------------------------------------------------
// GAT 3-layer forward. N=20000 nodes, E=320000 edges (+N self loops).
// Round 5: hierarchical CSR prefix-scan (the single-block scan was 46us on
// one CU); L2 logits fused into the L2 GEMM epilogue. bf16 edge gather.
// ---------------------------------------------------------------------------

#define LRELU(v) ((v) > 0.f ? (v) : 0.2f * (v))

__device__ __forceinline__ unsigned short f2b(float f) {
    unsigned u = __float_as_uint(f);
    unsigned r = (u + 0x7fffu + ((u >> 16) & 1u)) >> 16;   // RNE
    return (unsigned short)r;
}
__device__ __forceinline__ float bl(unsigned u) { return __uint_as_float(u << 16); }
__device__ __forceinline__ float bh(unsigned u) { return __uint_as_float(u & 0xffff0000u); }

// -------------------------- fills ------------------------------------------
__global__ void fill_u32_k(unsigned* p, unsigned v, int n) {
    int i = blockIdx.x * 256 + threadIdx.x;
    if (i < n) p[i] = v;
}

// -------------------------- CSR build --------------------------------------
__global__ void hist_k(const int* __restrict__ ei, int E, int N,
                       int* __restrict__ deg) {
    int e = blockIdx.x * 256 + threadIdx.x;
    if (e >= E + N) return;
    int d = (e < E) ? ei[E + e] : (e - E);
    atomicAdd(&deg[d], 1);
}

// ---- hierarchical exclusive scan over deg[N] (N <= 64*1024) ----
// A: per-1024-chunk sums. 256 thr/block, 4 elems/thread.
__global__ void scanA_k(const int* __restrict__ deg, int* __restrict__ bsum,
                        int N) {
    __shared__ int wsum[4];
    int tid = threadIdx.x;
    int base = blockIdx.x * 1024 + tid * 4;
    int4 v = {0, 0, 0, 0};
    if (base + 3 < N) v = *(const int4*)(deg + base);
    else {
        if (base < N)     v.x = deg[base];
        if (base + 1 < N) v.y = deg[base + 1];
        if (base + 2 < N) v.z = deg[base + 2];
    }
    int s = v.x + v.y + v.z + v.w;
    for (int off = 32; off; off >>= 1) s += __shfl_down(s, off);
    if ((tid & 63) == 0) wsum[tid >> 6] = s;
    __syncthreads();
    if (tid == 0) bsum[blockIdx.x] = wsum[0] + wsum[1] + wsum[2] + wsum[3];
}

// B: one wave scans the (<=64) chunk sums -> exclusive chunk offsets + total.
__global__ void scanB_k(const int* __restrict__ bsum, int* __restrict__ boff,
                        int nb, int* __restrict__ rowptrN) {
    int tid = threadIdx.x;             // 64
    int b = (tid < nb) ? bsum[tid] : 0;
    int v = b;
    for (int off = 1; off < 64; off <<= 1) {
        int t = __shfl_up(v, off);
        if (tid >= off) v += t;
    }
    if (tid < nb) boff[tid] = v - b;
    if (tid == 63) *rowptrN = v;
}

// C: per-chunk exclusive scan + chunk offset -> rowptr, cnt.
__global__ void scanC_k(const int* __restrict__ deg, const int* __restrict__ boff,
                        int* __restrict__ rowptr, int* __restrict__ cnt, int N) {
    __shared__ int part[256];
    int tid = threadIdx.x;
    int base = blockIdx.x * 1024 + tid * 4;
    int d0 = 0, d1 = 0, d2 = 0, d3 = 0;
    if (base + 3 < N) {
        int4 v = *(const int4*)(deg + base);
        d0 = v.x; d1 = v.y; d2 = v.z; d3 = v.w;
    } else {
        if (base < N)     d0 = deg[base];
        if (base + 1 < N) d1 = deg[base + 1];
        if (base + 2 < N) d2 = deg[base + 2];
    }
    part[tid] = d0 + d1 + d2 + d3;
    __syncthreads();
    for (int off = 1; off < 256; off <<= 1) {
        int t = (tid >= off) ? part[tid - off] : 0;
        __syncthreads();
        part[tid] += t;
        __syncthreads();
    }
    int pre = boff[blockIdx.x] + ((tid == 0) ? 0 : part[tid - 1]);
    if (base < N)     { rowptr[base] = pre;     cnt[base] = pre; }
    pre += d0;
    if (base + 1 < N) { rowptr[base + 1] = pre; cnt[base + 1] = pre; }
    pre += d1;
    if (base + 2 < N) { rowptr[base + 2] = pre; cnt[base + 2] = pre; }
    pre += d2;
    if (base + 3 < N) { rowptr[base + 3] = pre; cnt[base + 3] = pre; }
}

__global__ void scatter_k(const int* __restrict__ ei, int E, int N,
                          int* __restrict__ cnt, int* __restrict__ ssrc) {
    int e = blockIdx.x * 256 + threadIdx.x;
    if (e >= E + N) return;
    int s, d;
    if (e < E) { s = ei[e]; d = ei[E + e]; }
    else       { s = d = e - E; }
    int pos = atomicAdd(&cnt[d], 1);
    ssrc[pos] = s;
}

// ------------- tiled GEMM (OUT=256) + fused per-node logits -----------------
template <int IN>
__global__ __launch_bounds__(256) void gemm64_k(
        const float* __restrict__ X, const float* __restrict__ W,
        const float* __restrict__ as, const float* __restrict__ ad,
        __hip_bfloat16* __restrict__ Y,
        float* __restrict__ als, float* __restrict__ ald, int M) {
    constexpr int BM = 64, BN = 64, BK = 32, OUT = 256;
    __shared__ float Xs[BK][BM + 4];
    __shared__ float Ws[BK][BN + 4];
    const int tid = threadIdx.x;
    const int tx = tid & 15, ty = tid >> 4;
    const int row0 = blockIdx.x * BM, col0 = blockIdx.y * BN;
    const int lr = tid >> 2;           // X-load row 0..63
    const int lk = (tid & 3) * 8;      // X-load k offset {0,8,16,24}
    const int wr = tid >> 3;           // W-load k row 0..31
    const int wc = (tid & 7) * 8;      // W-load col offset {0..56}
    float acc[4][4] = {};
    for (int k0 = 0; k0 < IN; k0 += BK) {
        float4 xa = {0, 0, 0, 0}, xb = {0, 0, 0, 0};
        if (row0 + lr < M) {
            const float* xp = X + (size_t)(row0 + lr) * IN + k0 + lk;
            xa = *(const float4*)xp;
            xb = *(const float4*)(xp + 4);
        }
        const float* wp = W + (size_t)(k0 + wr) * OUT + col0 + wc;
        float4 wa = *(const float4*)wp;
        float4 wb = *(const float4*)(wp + 4);
        __syncthreads();
        Xs[lk + 0][lr] = xa.x; Xs[lk + 1][lr] = xa.y;
        Xs[lk + 2][lr] = xa.z; Xs[lk + 3][lr] = xa.w;
        Xs[lk + 4][lr] = xb.x; Xs[lk + 5][lr] = xb.y;
        Xs[lk + 6][lr] = xb.z; Xs[lk + 7][lr] = xb.w;
        *(float4*)&Ws[wr][wc] = wa;
        *(float4*)&Ws[wr][wc + 4] = wb;
        __syncthreads();
#pragma unroll
        for (int k = 0; k < BK; k++) {
            float4 a = *(const float4*)&Xs[k][ty * 4];
            float4 b = *(const float4*)&Ws[k][tx * 4];
            acc[0][0] += a.x * b.x; acc[0][1] += a.x * b.y;
            acc[0][2] += a.x * b.z; acc[0][3] += a.x * b.w;
            acc[1][0] += a.y * b.x; acc[1][1] += a.y * b.y;
            acc[1][2] += a.y * b.z; acc[1][3] += a.y * b.w;
            acc[2][0] += a.z * b.x; acc[2][1] += a.z * b.y;
            acc[2][2] += a.z * b.z; acc[2][3] += a.z * b.w;
            acc[3][0] += a.w * b.x; acc[3][1] += a.w * b.y;
            acc[3][2] += a.w * b.z; acc[3][3] += a.w * b.w;
        }
    }
#pragma unroll
    for (int i = 0; i < 4; i++) {
        int r = row0 + ty * 4 + i;
        if (r < M) {
            ushort4 v;
            v.x = f2b(acc[i][0]); v.y = f2b(acc[i][1]);
            v.z = f2b(acc[i][2]); v.w = f2b(acc[i][3]);
            *(ushort4*)((unsigned short*)Y + (size_t)r * OUT + col0 + tx * 4) = v;
        }
    }
    const int h = 2 * blockIdx.y + (tx >> 3);
    const int cmod = (tx * 4) & 31;
    float4 a4 = *(const float4*)(as + h * 32 + cmod);
    float4 d4 = *(const float4*)(ad + h * 32 + cmod);
#pragma unroll
    for (int i = 0; i < 4; i++) {
        float ps = acc[i][0] * a4.x + acc[i][1] * a4.y +
                   acc[i][2] * a4.z + acc[i][3] * a4.w;
        float pd = acc[i][0] * d4.x + acc[i][1] * d4.y +
                   acc[i][2] * d4.z + acc[i][3] * d4.w;
        ps += __shfl_xor(ps, 1); ps += __shfl_xor(ps, 2); ps += __shfl_xor(ps, 4);
        pd += __shfl_xor(pd, 1); pd += __shfl_xor(pd, 2); pd += __shfl_xor(pd, 4);
        int r = row0 + ty * 4 + i;
        if ((tx & 7) == 0 && r < M) {
            als[r * 8 + h] = ps;
            ald[r * 8 + h] = pd;
        }
    }
}

// --------- L2 GEMM (OUT=16) + fused H=1 logits in epilogue ------------------
template <int IN>
__global__ void gemm16_k(const float* __restrict__ X, const float* __restrict__ W,
                         const float* __restrict__ as, const float* __restrict__ ad,
                         float* __restrict__ Y,
                         float* __restrict__ als, float* __restrict__ ald, int M) {
    constexpr int ROWS = 32, OUT = 16, RPT = 2;
    __shared__ float xs[ROWS][IN];
    const int row0 = blockIdx.x * ROWS;
    const int tid = threadIdx.x;
    for (int idx = tid; idx < ROWS * IN; idx += 256) {
        int r = idx / IN, k = idx % IN;
        int gr = row0 + r;
        xs[r][k] = (gr < M) ? X[gr * IN + k] : 0.f;
    }
    __syncthreads();
    const int j = tid & 15;
    const int rbase = (tid >> 4) * RPT;
    float acc[RPT] = {};
    for (int k = 0; k < IN; k++) {
        float w = W[k * OUT + j];
#pragma unroll
        for (int r = 0; r < RPT; r++) acc[r] += xs[rbase + r][k] * w;
    }
    float a1 = as[j], d1 = ad[j];
#pragma unroll
    for (int r = 0; r < RPT; r++) {
        int gr = row0 + rbase + r;
        if (gr < M) Y[gr * OUT + j] = acc[r];
        float ps = acc[r] * a1, pd = acc[r] * d1;
#pragma unroll
        for (int off = 8; off; off >>= 1) {
            ps += __shfl_xor(ps, off, 16);
            pd += __shfl_xor(pd, off, 16);
        }
        if (j == 0 && gr < M) { als[gr] = ps; ald[gr] = pd; }
    }
}

// -------------------------- CSR aggregate, H=8 C=32, bf16 feat --------------
__global__ void agg8_csr_k(const int* __restrict__ rowptr,
                           const int* __restrict__ ssrc,
                           const float* __restrict__ als,
                           const float* __restrict__ ald,
                           const __hip_bfloat16* __restrict__ feat,
                           float* __restrict__ agg, int N) {
    int lane = threadIdx.x & 63;
    int n = blockIdx.x * 4 + (threadIdx.x >> 6);
    if (n >= N) return;
    const int r0 = rowptr[n], r1 = rowptr[n + 1];
    const int sub = lane >> 5;         // which edge of the pair
    const int l = lane & 31;
    const int h = l >> 2;              // head for max AND channels
    const int c0 = l * 8;              // 8 bf16 channels
    const float adh = ald[n * 8 + h];

    float mh = -1e30f;
    for (int e = r0 + sub; e < r1; e += 2) {
        int s = ssrc[e];
        float v = als[s * 8 + h] + adh;
        mh = fmaxf(mh, LRELU(v));
    }
    mh = fmaxf(mh, __shfl_xor(mh, 32));   // merge the two half-waves

    float acc[8] = {};
    float den = 0.f;
    const unsigned short* fp = (const unsigned short*)feat;
    for (int e = r0 + sub; e < r1; e += 2) {
        int s = ssrc[e];
        float v = als[s * 8 + h] + adh;
        v = LRELU(v);
        float p = __expf(v - mh);
        den += p;
        uint4 f = *(const uint4*)(fp + (size_t)s * 256 + c0);
        acc[0] += bl(f.x) * p; acc[1] += bh(f.x) * p;
        acc[2] += bl(f.y) * p; acc[3] += bh(f.y) * p;
        acc[4] += bl(f.z) * p; acc[5] += bh(f.z) * p;
        acc[6] += bl(f.w) * p; acc[7] += bh(f.w) * p;
    }
    den += __shfl_xor(den, 32);
#pragma unroll
    for (int j = 0; j < 8; j++) acc[j] += __shfl_xor(acc[j], 32);
    float inv = 1.f / den;
    float4 o0 = {acc[0] * inv, acc[1] * inv, acc[2] * inv, acc[3] * inv};
    float4 o1 = {acc[4] * inv, acc[5] * inv, acc[6] * inv, acc[7] * inv};
    float* op = agg + (size_t)n * 256 + c0;
    *(float4*)op = o0;
    *(float4*)(op + 4) = o1;
}

// -------------------------- CSR aggregate + log_softmax, H=1 C=16 -----------
__global__ void agg1_ls_k(const int* __restrict__ rowptr,
                          const int* __restrict__ ssrc,
                          const float* __restrict__ als,
                          const float* __restrict__ ald,
                          const float* __restrict__ feat,
                          const float* __restrict__ b2,
                          float* __restrict__ out, int N) {
    int lane = threadIdx.x & 63;
    int n = blockIdx.x * 4 + (threadIdx.x >> 6);
    if (n >= N) return;
    const int r0 = rowptr[n], r1 = rowptr[n + 1];
    float adh = ald[n];

    float mh = -1e30f;
    for (int e = r0 + lane; e < r1; e += 64) {
        int s = ssrc[e];
        float v = als[s] + adh;
        mh = fmaxf(mh, LRELU(v));
    }
#pragma unroll
    for (int off = 32; off; off >>= 1) mh = fmaxf(mh, __shfl_xor(mh, off));

    int slot = lane >> 4, c = lane & 15;
    float acc = 0.f, den = 0.f;
    for (int e = r0 + slot; e < r1; e += 4) {
        int s = ssrc[e];
        float v = als[s] + adh;
        v = LRELU(v);
        float p = __expf(v - mh);
        den += p;
        acc += feat[s * 16 + c] * p;
    }
    acc += __shfl_xor(acc, 16); acc += __shfl_xor(acc, 32);
    den += __shfl_xor(den, 16); den += __shfl_xor(den, 32);

    float v = acc / den + b2[c];
    float mm = v;
#pragma unroll
    for (int off = 8; off; off >>= 1) mm = fmaxf(mm, __shfl_xor(mm, off, 16));
    float ex = __expf(v - mm);
    float ssum = ex;
#pragma unroll
    for (int off = 8; off; off >>= 1) ssum += __shfl_xor(ssum, off, 16);
    if (lane < 16) out[n * 16 + c] = v - mm - logf(ssum);
}

// -------------------------- batchnorm ---------------------------------------
__global__ void bn_stats_k(const float* __restrict__ agg,
                           const float* __restrict__ b,
                           float* __restrict__ stats, int N) {
    int ch = threadIdx.x;             // 256
    int r0 = blockIdx.x * 64;
    int r1 = r0 + 64 < N ? r0 + 64 : N;
    float s = 0.f, s2 = 0.f;
    for (int r = r0; r < r1; r++) {
        float v = agg[r * 256 + ch] + b[ch];
        s += v; s2 += v * v;
    }
    atomicAdd(&stats[ch], s);
    atomicAdd(&stats[256 + ch], s2);
}

// in-place safe (each thread reads/writes its own element)
__global__ void bn_apply_k(const float* __restrict__ agg,
                           const float* __restrict__ b,
                           const float* __restrict__ stats,
                           const float* __restrict__ g,
                           const float* __restrict__ be,
                           float* __restrict__ outp, int N) {
    int gid = blockIdx.x * 256 + threadIdx.x;
    if (gid >= N * 256) return;
    int ch = gid & 255;
    float invN = 1.f / (float)N;
    float mu = stats[ch] * invN;
    float var = stats[256 + ch] * invN - mu * mu;
    float v = (agg[gid] + b[ch] - mu) * rsqrtf(var + 1e-5f) * g[ch] + be[ch];
    outp[gid] = v > 0.f ? v : 0.f;
}

// ---------------------------------------------------------------------------
extern "C" void kernel_launch(void* const* d_in, const int* in_sizes, int n_in,
                              void* d_out, int out_size, void* d_ws, size_t ws_size,
                              hipStream_t stream) {
    const float* x   = (const float*)d_in[0];
    const int*   ei  = (const int*)d_in[1];
    const float* W0  = (const float*)d_in[2];
    const float* as0 = (const float*)d_in[3];
    const float* ad0 = (const float*)d_in[4];
    const float* b0  = (const float*)d_in[5];
    const float* g0  = (const float*)d_in[6];
    const float* be0 = (const float*)d_in[7];
    const float* W1  = (const float*)d_in[8];
    const float* as1 = (const float*)d_in[9];
    const float* ad1 = (const float*)d_in[10];
    const float* b1  = (const float*)d_in[11];
    const float* g1  = (const float*)d_in[12];
    const float* be1 = (const float*)d_in[13];
    const float* W2  = (const float*)d_in[14];
    const float* as2 = (const float*)d_in[15];
    const float* ad2 = (const float*)d_in[16];
    const float* b2  = (const float*)d_in[17];
    float* out = (float*)d_out;

    const int N = in_sizes[0] / 128;       // 20000
    const int E = in_sizes[1] / 2;         // 320000
    const int ET = E + N;                  // with self loops

    float* ws = (float*)d_ws;
    size_t o = 0;
    float* aggA = ws + o;  o += (size_t)N * 256;   // agg out / BN in-place / gemm in
    __hip_bfloat16* hb16 = (__hip_bfloat16*)(ws + o); o += (size_t)N * 128; // bf16 feat
    float* als  = ws + o;  o += (size_t)N * 8;
    float* ald  = ws + o;  o += (size_t)N * 8;
    float* stats = ws + o; o += 512;
    float* h2   = ws + o;  o += (size_t)N * 16;
    float* als2 = ws + o;  o += (size_t)N;
    float* ald2 = ws + o;  o += (size_t)N;
    int* deg    = (int*)(ws + o); o += (size_t)N;
    int* rowptr = (int*)(ws + o); o += (size_t)N + 1;
    int* cnt    = (int*)(ws + o); o += (size_t)N;
    int* ssrc   = (int*)(ws + o); o += (size_t)ET;
    int* bsum   = (int*)(ws + o); o += 64;
    int* boff   = (int*)(ws + o); o += 64;

    const int gE    = (ET + 255) / 256;
    const int gN256 = (N * 256 + 255) / 256;
    const int gBN   = (N + 63) / 64;
    const int gWave = (N + 3) / 4;         // 1 wave per node, 4 waves/block
    const int nb    = (N + 1023) / 1024;   // scan chunks (<=64)
    dim3 gGemm((N + 63) / 64, 4);

    // ---------------- CSR build (dst-sorted) ----------------
    fill_u32_k<<<(N + 255) / 256, 256, 0, stream>>>((unsigned*)deg, 0u, N);
    hist_k<<<gE, 256, 0, stream>>>(ei, E, N, deg);
    scanA_k<<<nb, 256, 0, stream>>>(deg, bsum, N);
    scanB_k<<<1, 64, 0, stream>>>(bsum, boff, nb, rowptr + N);
    scanC_k<<<nb, 256, 0, stream>>>(deg, boff, rowptr, cnt, N);
    scatter_k<<<gE, 256, 0, stream>>>(ei, E, N, cnt, ssrc);

    // ---------------- Layer 0 ----------------
    gemm64_k<128><<<gGemm, 256, 0, stream>>>(x, W0, as0, ad0, hb16, als, ald, N);
    agg8_csr_k<<<gWave, 256, 0, stream>>>(rowptr, ssrc, als, ald, hb16, aggA, N);
    fill_u32_k<<<2, 256, 0, stream>>>((unsigned*)stats, 0u, 512);
    bn_stats_k<<<gBN, 256, 0, stream>>>(aggA, b0, stats, N);
    bn_apply_k<<<gN256, 256, 0, stream>>>(aggA, b0, stats, g0, be0, aggA, N);

    // ---------------- Layer 1 ----------------
    gemm64_k<256><<<gGemm, 256, 0, stream>>>(aggA, W1, as1, ad1, hb16, als, ald, N);
    agg8_csr_k<<<gWave, 256, 0, stream>>>(rowptr, ssrc, als, ald, hb16, aggA, N);
    fill_u32_k<<<2, 256, 0, stream>>>((unsigned*)stats, 0u, 512);
    bn_stats_k<<<gBN, 256, 0, stream>>>(aggA, b1, stats, N);
    bn_apply_k<<<gN256, 256, 0, stream>>>(aggA, b1, stats, g1, be1, aggA, N);

    // ---------------- Layer 2 ----------------
    gemm16_k<256><<<(N + 31) / 32, 256, 0, stream>>>(aggA, W2, as2, ad2, h2,
                                                     als2, ald2, N);
    agg1_ls_k<<<gWave, 256, 0, stream>>>(rowptr, ssrc, als2, ald2, h2, b2, out, N);
}

// Round 6
// 269.236 us; speedup vs baseline: 3.7000x; 1.1348x over previous
//
#include <hip/hip_runtime.h>
#include <hip/hip_bf16.h>
#include <math.h>

// ---------------------------------------------------------------------------
// GAT 3-layer forward. N=20000 nodes, E=320000 edges (+N self loops).
// Round 6: bf16 MFMA GEMM (16x16x32) for the two 256-wide layers, fused
// attention-logit epilogue. W pre-transposed to [OUT][IN] bf16 once per call;
// BN-apply emits bf16 activations. CSR gather-reduce aggregation (bf16 feat).
// ---------------------------------------------------------------------------

#define LRELU(v) ((v) > 0.f ? (v) : 0.2f * (v))

typedef __attribute__((ext_vector_type(8))) short short8v;   // 8 bf16
typedef __attribute__((ext_vector_type(4))) float f32x4;

__device__ __forceinline__ unsigned short f2b(float f) {
    unsigned u = __float_as_uint(f);
    unsigned r = (u + 0x7fffu + ((u >> 16) & 1u)) >> 16;   // RNE
    return (unsigned short)r;
}
__device__ __forceinline__ float bl(unsigned u) { return __uint_as_float(u << 16); }
__device__ __forceinline__ float bh(unsigned u) { return __uint_as_float(u & 0xffff0000u); }
__device__ __forceinline__ float b2f(unsigned short u) {
    return __uint_as_float((unsigned)u << 16);
}

// -------------------------- fills / converts --------------------------------
__global__ void fill_u32_k(unsigned* p, unsigned v, int n) {
    int i = blockIdx.x * 256 + threadIdx.x;
    if (i < n) p[i] = v;
}

// fp32 -> bf16, 4 elems/thread (n multiple of 4)
__global__ void cvt_bf16_k(const float* __restrict__ in,
                           unsigned short* __restrict__ out, int n) {
    int i = (blockIdx.x * 256 + threadIdx.x) * 4;
    if (i >= n) return;
    float4 v = *(const float4*)(in + i);
    ushort4 o;
    o.x = f2b(v.x); o.y = f2b(v.y); o.z = f2b(v.z); o.w = f2b(v.w);
    *(ushort4*)(out + i) = o;
}

// W [IN][OUT] fp32 -> Wt [OUT][IN] bf16 (32x32 LDS tile transpose)
template <int IN, int OUT>
__global__ void cvt_wt_k(const float* __restrict__ W,
                         unsigned short* __restrict__ Wt) {
    __shared__ float t[32][33];
    int tx = threadIdx.x & 31, ty = threadIdx.x >> 5;   // 32 x 8
    int c0 = blockIdx.x * 32;                            // along OUT
    int r0 = blockIdx.y * 32;                            // along IN
#pragma unroll
    for (int j = 0; j < 32; j += 8)
        t[ty + j][tx] = W[(size_t)(r0 + ty + j) * OUT + c0 + tx];
    __syncthreads();
#pragma unroll
    for (int j = 0; j < 32; j += 8)
        Wt[(size_t)(c0 + ty + j) * IN + r0 + tx] = f2b(t[tx][ty + j]);
}

// -------------------------- CSR build --------------------------------------
__global__ void hist_k(const int* __restrict__ ei, int E, int N,
                       int* __restrict__ deg) {
    int e = blockIdx.x * 256 + threadIdx.x;
    if (e >= E + N) return;
    int d = (e < E) ? ei[E + e] : (e - E);
    atomicAdd(&deg[d], 1);
}

__global__ void scanA_k(const int* __restrict__ deg, int* __restrict__ bsum,
                        int N) {
    __shared__ int wsum[4];
    int tid = threadIdx.x;
    int base = blockIdx.x * 1024 + tid * 4;
    int4 v = {0, 0, 0, 0};
    if (base + 3 < N) v = *(const int4*)(deg + base);
    else {
        if (base < N)     v.x = deg[base];
        if (base + 1 < N) v.y = deg[base + 1];
        if (base + 2 < N) v.z = deg[base + 2];
    }
    int s = v.x + v.y + v.z + v.w;
    for (int off = 32; off; off >>= 1) s += __shfl_down(s, off);
    if ((tid & 63) == 0) wsum[tid >> 6] = s;
    __syncthreads();
    if (tid == 0) bsum[blockIdx.x] = wsum[0] + wsum[1] + wsum[2] + wsum[3];
}

__global__ void scanB_k(const int* __restrict__ bsum, int* __restrict__ boff,
                        int nb, int* __restrict__ rowptrN) {
    int tid = threadIdx.x;             // 64
    int b = (tid < nb) ? bsum[tid] : 0;
    int v = b;
    for (int off = 1; off < 64; off <<= 1) {
        int t = __shfl_up(v, off);
        if (tid >= off) v += t;
    }
    if (tid < nb) boff[tid] = v - b;
    if (tid == 63) *rowptrN = v;
}

__global__ void scanC_k(const int* __restrict__ deg, const int* __restrict__ boff,
                        int* __restrict__ rowptr, int* __restrict__ cnt, int N) {
    __shared__ int part[256];
    int tid = threadIdx.x;
    int base = blockIdx.x * 1024 + tid * 4;
    int d0 = 0, d1 = 0, d2 = 0, d3 = 0;
    if (base + 3 < N) {
        int4 v = *(const int4*)(deg + base);
        d0 = v.x; d1 = v.y; d2 = v.z; d3 = v.w;
    } else {
        if (base < N)     d0 = deg[base];
        if (base + 1 < N) d1 = deg[base + 1];
        if (base + 2 < N) d2 = deg[base + 2];
    }
    part[tid] = d0 + d1 + d2 + d3;
    __syncthreads();
    for (int off = 1; off < 256; off <<= 1) {
        int t = (tid >= off) ? part[tid - off] : 0;
        __syncthreads();
        part[tid] += t;
        __syncthreads();
    }
    int pre = boff[blockIdx.x] + ((tid == 0) ? 0 : part[tid - 1]);
    if (base < N)     { rowptr[base] = pre;     cnt[base] = pre; }
    pre += d0;
    if (base + 1 < N) { rowptr[base + 1] = pre; cnt[base + 1] = pre; }
    pre += d1;
    if (base + 2 < N) { rowptr[base + 2] = pre; cnt[base + 2] = pre; }
    pre += d2;
    if (base + 3 < N) { rowptr[base + 3] = pre; cnt[base + 3] = pre; }
}

__global__ void scatter_k(const int* __restrict__ ei, int E, int N,
                          int* __restrict__ cnt, int* __restrict__ ssrc) {
    int e = blockIdx.x * 256 + threadIdx.x;
    if (e >= E + N) return;
    int s, d;
    if (e < E) { s = ei[e]; d = ei[E + e]; }
    else       { s = d = e - E; }
    int pos = atomicAdd(&cnt[d], 1);
    ssrc[pos] = s;
}

// --------- bf16 MFMA GEMM (OUT=256) + fused per-node logits -----------------
// 64x64 tile, BK=64, 4 waves; wave (wr,wc) owns a 32x32 quadrant = 2x2
// 16x16x32 fragments. Xb [M][IN] bf16, Wt [256][IN] bf16 (pre-transposed).
// C/D layout: col = lane&15, row = (lane>>4)*4 + reg  [m89].
// Wave wc owns head h = 2*blockIdx.y + wc completely -> logits in epilogue.
template <int IN>
__global__ __launch_bounds__(256) void gemm_mfma_k(
        const unsigned short* __restrict__ Xb,
        const unsigned short* __restrict__ Wt,
        const float* __restrict__ as, const float* __restrict__ ad,
        unsigned short* __restrict__ Y,
        float* __restrict__ als, float* __restrict__ ald, int M) {
    constexpr int LDT = 72;            // padded stride in bf16 (144 B, 16B-mult)
    __shared__ unsigned short Xs[64 * LDT];
    __shared__ unsigned short Ws[64 * LDT];
    const int tid = threadIdx.x;
    const int lane = tid & 63, wid = tid >> 6;
    const int wr = wid >> 1, wc = wid & 1;
    const int cl = lane & 15, kg = lane >> 4;
    const int row0 = blockIdx.x * 64, col0 = blockIdx.y * 64;
    const int sr = tid >> 3;           // staging row 0..31
    const int sk = (tid & 7) * 8;      // staging k offset

    f32x4 acc[2][2] = {};

    for (int k0 = 0; k0 < IN; k0 += 64) {
        uint4 xv0 = {0, 0, 0, 0}, xv1 = {0, 0, 0, 0};
        int xr0 = row0 + sr, xr1 = row0 + sr + 32;
        if (xr0 < M) xv0 = *(const uint4*)&Xb[(size_t)xr0 * IN + k0 + sk];
        if (xr1 < M) xv1 = *(const uint4*)&Xb[(size_t)xr1 * IN + k0 + sk];
        uint4 wv0 = *(const uint4*)&Wt[(size_t)(col0 + sr) * IN + k0 + sk];
        uint4 wv1 = *(const uint4*)&Wt[(size_t)(col0 + sr + 32) * IN + k0 + sk];
        __syncthreads();
        *(uint4*)&Xs[sr * LDT + sk] = xv0;
        *(uint4*)&Xs[(sr + 32) * LDT + sk] = xv1;
        *(uint4*)&Ws[sr * LDT + sk] = wv0;
        *(uint4*)&Ws[(sr + 32) * LDT + sk] = wv1;
        __syncthreads();
#pragma unroll
        for (int kk = 0; kk < 64; kk += 32) {
            const int ko = kk + kg * 8;
            short8v a0 = *(const short8v*)&Xs[(wr * 32 + cl) * LDT + ko];
            short8v a1 = *(const short8v*)&Xs[(wr * 32 + 16 + cl) * LDT + ko];
            short8v b0 = *(const short8v*)&Ws[(wc * 32 + cl) * LDT + ko];
            short8v b1 = *(const short8v*)&Ws[(wc * 32 + 16 + cl) * LDT + ko];
            acc[0][0] = __builtin_amdgcn_mfma_f32_16x16x32_bf16(a0, b0, acc[0][0], 0, 0, 0);
            acc[0][1] = __builtin_amdgcn_mfma_f32_16x16x32_bf16(a0, b1, acc[0][1], 0, 0, 0);
            acc[1][0] = __builtin_amdgcn_mfma_f32_16x16x32_bf16(a1, b0, acc[1][0], 0, 0, 0);
            acc[1][1] = __builtin_amdgcn_mfma_f32_16x16x32_bf16(a1, b1, acc[1][1], 0, 0, 0);
        }
    }

    // Y store (bf16 feat table)
#pragma unroll
    for (int mt = 0; mt < 2; mt++)
#pragma unroll
        for (int j = 0; j < 4; j++) {
            int r = row0 + wr * 32 + mt * 16 + kg * 4 + j;
            if (r < M) {
#pragma unroll
                for (int nt = 0; nt < 2; nt++)
                    Y[(size_t)r * 256 + col0 + wc * 32 + nt * 16 + cl] =
                        f2b(acc[mt][nt][j]);
            }
        }

    // fused attention logits for head h (wave-owned)
    const int h = 2 * blockIdx.y + wc;
    float as0v = as[h * 32 + cl], as1v = as[h * 32 + 16 + cl];
    float ad0v = ad[h * 32 + cl], ad1v = ad[h * 32 + 16 + cl];
#pragma unroll
    for (int mt = 0; mt < 2; mt++)
#pragma unroll
        for (int j = 0; j < 4; j++) {
            float ps = acc[mt][0][j] * as0v + acc[mt][1][j] * as1v;
            float pd = acc[mt][0][j] * ad0v + acc[mt][1][j] * ad1v;
            ps += __shfl_xor(ps, 1); ps += __shfl_xor(ps, 2);
            ps += __shfl_xor(ps, 4); ps += __shfl_xor(ps, 8);
            pd += __shfl_xor(pd, 1); pd += __shfl_xor(pd, 2);
            pd += __shfl_xor(pd, 4); pd += __shfl_xor(pd, 8);
            int r = row0 + wr * 32 + mt * 16 + kg * 4 + j;
            if (cl == 0 && r < M) {
                als[r * 8 + h] = ps;
                ald[r * 8 + h] = pd;
            }
        }
}

// --------- L2 GEMM (OUT=16, bf16 X) + fused H=1 logits ----------------------
template <int IN>
__global__ void gemm16_k(const unsigned short* __restrict__ X,
                         const float* __restrict__ W,
                         const float* __restrict__ as, const float* __restrict__ ad,
                         float* __restrict__ Y,
                         float* __restrict__ als, float* __restrict__ ald, int M) {
    constexpr int ROWS = 32, OUT = 16, RPT = 2;
    __shared__ float xs[ROWS][IN];
    const int row0 = blockIdx.x * ROWS;
    const int tid = threadIdx.x;
    for (int idx = tid; idx < ROWS * IN; idx += 256) {
        int r = idx / IN, k = idx % IN;
        int gr = row0 + r;
        xs[r][k] = (gr < M) ? b2f(X[(size_t)gr * IN + k]) : 0.f;
    }
    __syncthreads();
    const int j = tid & 15;
    const int rbase = (tid >> 4) * RPT;
    float acc[RPT] = {};
    for (int k = 0; k < IN; k++) {
        float w = W[k * OUT + j];
#pragma unroll
        for (int r = 0; r < RPT; r++) acc[r] += xs[rbase + r][k] * w;
    }
    float a1 = as[j], d1 = ad[j];
#pragma unroll
    for (int r = 0; r < RPT; r++) {
        int gr = row0 + rbase + r;
        if (gr < M) Y[gr * OUT + j] = acc[r];
        float ps = acc[r] * a1, pd = acc[r] * d1;
#pragma unroll
        for (int off = 8; off; off >>= 1) {
            ps += __shfl_xor(ps, off, 16);
            pd += __shfl_xor(pd, off, 16);
        }
        if (j == 0 && gr < M) { als[gr] = ps; ald[gr] = pd; }
    }
}

// -------------------------- CSR aggregate, H=8 C=32, bf16 feat --------------
__global__ void agg8_csr_k(const int* __restrict__ rowptr,
                           const int* __restrict__ ssrc,
                           const float* __restrict__ als,
                           const float* __restrict__ ald,
                           const unsigned short* __restrict__ feat,
                           float* __restrict__ agg, int N) {
    int lane = threadIdx.x & 63;
    int n = blockIdx.x * 4 + (threadIdx.x >> 6);
    if (n >= N) return;
    const int r0 = rowptr[n], r1 = rowptr[n + 1];
    const int sub = lane >> 5;         // which edge of the pair
    const int l = lane & 31;
    const int h = l >> 2;              // head for max AND channels
    const int c0 = l * 8;              // 8 bf16 channels
    const float adh = ald[n * 8 + h];

    float mh = -1e30f;
    for (int e = r0 + sub; e < r1; e += 2) {
        int s = ssrc[e];
        float v = als[s * 8 + h] + adh;
        mh = fmaxf(mh, LRELU(v));
    }
    mh = fmaxf(mh, __shfl_xor(mh, 32));

    float acc[8] = {};
    float den = 0.f;
    for (int e = r0 + sub; e < r1; e += 2) {
        int s = ssrc[e];
        float v = als[s * 8 + h] + adh;
        v = LRELU(v);
        float p = __expf(v - mh);
        den += p;
        uint4 f = *(const uint4*)(feat + (size_t)s * 256 + c0);
        acc[0] += bl(f.x) * p; acc[1] += bh(f.x) * p;
        acc[2] += bl(f.y) * p; acc[3] += bh(f.y) * p;
        acc[4] += bl(f.z) * p; acc[5] += bh(f.z) * p;
        acc[6] += bl(f.w) * p; acc[7] += bh(f.w) * p;
    }
    den += __shfl_xor(den, 32);
#pragma unroll
    for (int j = 0; j < 8; j++) acc[j] += __shfl_xor(acc[j], 32);
    float inv = 1.f / den;
    float4 o0 = {acc[0] * inv, acc[1] * inv, acc[2] * inv, acc[3] * inv};
    float4 o1 = {acc[4] * inv, acc[5] * inv, acc[6] * inv, acc[7] * inv};
    float* op = agg + (size_t)n * 256 + c0;
    *(float4*)op = o0;
    *(float4*)(op + 4) = o1;
}

// -------------------------- CSR aggregate + log_softmax, H=1 C=16 -----------
__global__ void agg1_ls_k(const int* __restrict__ rowptr,
                          const int* __restrict__ ssrc,
                          const float* __restrict__ als,
                          const float* __restrict__ ald,
                          const float* __restrict__ feat,
                          const float* __restrict__ b2,
                          float* __restrict__ out, int N) {
    int lane = threadIdx.x & 63;
    int n = blockIdx.x * 4 + (threadIdx.x >> 6);
    if (n >= N) return;
    const int r0 = rowptr[n], r1 = rowptr[n + 1];
    float adh = ald[n];

    float mh = -1e30f;
    for (int e = r0 + lane; e < r1; e += 64) {
        int s = ssrc[e];
        float v = als[s] + adh;
        mh = fmaxf(mh, LRELU(v));
    }
#pragma unroll
    for (int off = 32; off; off >>= 1) mh = fmaxf(mh, __shfl_xor(mh, off));

    int slot = lane >> 4, c = lane & 15;
    float acc = 0.f, den = 0.f;
    for (int e = r0 + slot; e < r1; e += 4) {
        int s = ssrc[e];
        float v = als[s] + adh;
        v = LRELU(v);
        float p = __expf(v - mh);
        den += p;
        acc += feat[s * 16 + c] * p;
    }
    acc += __shfl_xor(acc, 16); acc += __shfl_xor(acc, 32);
    den += __shfl_xor(den, 16); den += __shfl_xor(den, 32);

    float v = acc / den + b2[c];
    float mm = v;
#pragma unroll
    for (int off = 8; off; off >>= 1) mm = fmaxf(mm, __shfl_xor(mm, off, 16));
    float ex = __expf(v - mm);
    float ssum = ex;
#pragma unroll
    for (int off = 8; off; off >>= 1) ssum += __shfl_xor(ssum, off, 16);
    if (lane < 16) out[n * 16 + c] = v - mm - logf(ssum);
}

// -------------------------- batchnorm ---------------------------------------
__global__ void bn_stats_k(const float* __restrict__ agg,
                           const float* __restrict__ b,
                           float* __restrict__ stats, int N) {
    int ch = threadIdx.x;             // 256
    int r0 = blockIdx.x * 64;
    int r1 = r0 + 64 < N ? r0 + 64 : N;
    float s = 0.f, s2 = 0.f;
    for (int r = r0; r < r1; r++) {
        float v = agg[r * 256 + ch] + b[ch];
        s += v; s2 += v * v;
    }
    atomicAdd(&stats[ch], s);
    atomicAdd(&stats[256 + ch], s2);
}

// BN + bias + ReLU, writes bf16 activations (next GEMM input)
__global__ void bn_apply_k(const float* __restrict__ agg,
                           const float* __restrict__ b,
                           const float* __restrict__ stats,
                           const float* __restrict__ g,
                           const float* __restrict__ be,
                           unsigned short* __restrict__ outp, int N) {
    int gid = blockIdx.x * 256 + threadIdx.x;
    if (gid >= N * 256) return;
    int ch = gid & 255;
    float invN = 1.f / (float)N;
    float mu = stats[ch] * invN;
    float var = stats[256 + ch] * invN - mu * mu;
    float v = (agg[gid] + b[ch] - mu) * rsqrtf(var + 1e-5f) * g[ch] + be[ch];
    outp[gid] = f2b(v > 0.f ? v : 0.f);
}

// ---------------------------------------------------------------------------
extern "C" void kernel_launch(void* const* d_in, const int* in_sizes, int n_in,
                              void* d_out, int out_size, void* d_ws, size_t ws_size,
                              hipStream_t stream) {
    const float* x   = (const float*)d_in[0];
    const int*   ei  = (const int*)d_in[1];
    const float* W0  = (const float*)d_in[2];
    const float* as0 = (const float*)d_in[3];
    const float* ad0 = (const float*)d_in[4];
    const float* b0  = (const float*)d_in[5];
    const float* g0  = (const float*)d_in[6];
    const float* be0 = (const float*)d_in[7];
    const float* W1  = (const float*)d_in[8];
    const float* as1 = (const float*)d_in[9];
    const float* ad1 = (const float*)d_in[10];
    const float* b1  = (const float*)d_in[11];
    const float* g1  = (const float*)d_in[12];
    const float* be1 = (const float*)d_in[13];
    const float* W2  = (const float*)d_in[14];
    const float* as2 = (const float*)d_in[15];
    const float* ad2 = (const float*)d_in[16];
    const float* b2  = (const float*)d_in[17];
    float* out = (float*)d_out;

    const int N = in_sizes[0] / 128;       // 20000
    const int E = in_sizes[1] / 2;         // 320000
    const int ET = E + N;                  // with self loops

    float* ws = (float*)d_ws;
    size_t o = 0;
    float* aggA = ws + o;  o += (size_t)N * 256;                 // fp32 aggregate
    unsigned short* hb16 = (unsigned short*)(ws + o); o += (size_t)N * 128; // feat
    unsigned short* xb16 = (unsigned short*)(ws + o); o += (size_t)N * 128; // BN out
    unsigned short* xb0  = (unsigned short*)(ws + o); o += (size_t)N * 64;  // x bf16
    unsigned short* Wt0  = (unsigned short*)(ws + o); o += 256 * 128 / 2;
    unsigned short* Wt1  = (unsigned short*)(ws + o); o += 256 * 256 / 2;
    float* als  = ws + o;  o += (size_t)N * 8;
    float* ald  = ws + o;  o += (size_t)N * 8;
    float* stats = ws + o; o += 512;
    float* h2   = ws + o;  o += (size_t)N * 16;
    float* als2 = ws + o;  o += (size_t)N;
    float* ald2 = ws + o;  o += (size_t)N;
    int* deg    = (int*)(ws + o); o += (size_t)N;
    int* rowptr = (int*)(ws + o); o += (size_t)N + 1;
    int* cnt    = (int*)(ws + o); o += (size_t)N;
    int* ssrc   = (int*)(ws + o); o += (size_t)ET;
    int* bsum   = (int*)(ws + o); o += 64;
    int* boff   = (int*)(ws + o); o += 64;

    const int gE    = (ET + 255) / 256;
    const int gN256 = (N * 256 + 255) / 256;
    const int gBN   = (N + 63) / 64;
    const int gWave = (N + 3) / 4;
    const int nb    = (N + 1023) / 1024;
    dim3 gGemm((N + 63) / 64, 4);

    // ---------------- CSR build (dst-sorted) ----------------
    fill_u32_k<<<(N + 255) / 256, 256, 0, stream>>>((unsigned*)deg, 0u, N);
    hist_k<<<gE, 256, 0, stream>>>(ei, E, N, deg);
    scanA_k<<<nb, 256, 0, stream>>>(deg, bsum, N);
    scanB_k<<<1, 64, 0, stream>>>(bsum, boff, nb, rowptr + N);
    scanC_k<<<nb, 256, 0, stream>>>(deg, boff, rowptr, cnt, N);
    scatter_k<<<gE, 256, 0, stream>>>(ei, E, N, cnt, ssrc);

    // ---------------- weight / input conversion ----------------
    cvt_bf16_k<<<(N * 128 / 4 + 255) / 256, 256, 0, stream>>>(x, xb0, N * 128);
    cvt_wt_k<128, 256><<<dim3(8, 4), 256, 0, stream>>>(W0, Wt0);
    cvt_wt_k<256, 256><<<dim3(8, 8), 256, 0, stream>>>(W1, Wt1);

    // ---------------- Layer 0 ----------------
    gemm_mfma_k<128><<<gGemm, 256, 0, stream>>>(xb0, Wt0, as0, ad0, hb16,
                                                als, ald, N);
    agg8_csr_k<<<gWave, 256, 0, stream>>>(rowptr, ssrc, als, ald, hb16, aggA, N);
    fill_u32_k<<<2, 256, 0, stream>>>((unsigned*)stats, 0u, 512);
    bn_stats_k<<<gBN, 256, 0, stream>>>(aggA, b0, stats, N);
    bn_apply_k<<<gN256, 256, 0, stream>>>(aggA, b0, stats, g0, be0, xb16, N);

    // ---------------- Layer 1 ----------------
    gemm_mfma_k<256><<<gGemm, 256, 0, stream>>>(xb16, Wt1, as1, ad1, hb16,
                                                als, ald, N);
    agg8_csr_k<<<gWave, 256, 0, stream>>>(rowptr, ssrc, als, ald, hb16, aggA, N);
    fill_u32_k<<<2, 256, 0, stream>>>((unsigned*)stats, 0u, 512);
    bn_stats_k<<<gBN, 256, 0, stream>>>(aggA, b1, stats, N);
    bn_apply_k<<<gN256, 256, 0, stream>>>(aggA, b1, stats, g1, be1, xb16, N);

    // ---------------- Layer 2 ----------------
    gemm16_k<256><<<(N + 31) / 32, 256, 0, stream>>>(xb16, W2, as2, ad2, h2,
                                                     als2, ald2, N);
    agg1_ls_k<<<gWave, 256, 0, stream>>>(rowptr, ssrc, als2, ald2, h2, b2, out, N);
}